// Round 9
// baseline (553.368 us; speedup 1.0000x reference)
//
#include <hip/hip_runtime.h>
#include <math.h>

// ---------------------------------------------------------------------------
// VideoChat3 vision encoder block, bf16-MFMA pipeline. Round 16:
//  - DIAGNOSTIC ROUND. r8 banked 490.7us (best). Eight schedule variants all
//    sit at 23-27% MfmaUtil (~605 TF FC0) = the known 2-phase structural
//    ceiling (m233/m230). Schedule knobs are exhausted; per rule #8, this
//    round MEASURES the decomposition instead of guessing a 9th schedule.
//  - Pipeline = r15 byte-identical (490.7us). Appended: abl_stage = bt8's
//    staging+vmcnt+barrier skeleton with ds_read/MFMA deleted, 3 K-sweeps
//    (long enough to surface in top-5), scratch output in dead workspace,
//    launched AFTER FC1 so real dispatches are unperturbed.
//  - Readout: staging_fraction of FC0 ~ D_abl/(3*113us). D>=270 => staging-
//    bound (fix: reg-staging / fewer staged bytes). Absent from top-5 =>
//    staging <33% => next round ablates the ds_read/MFMA side.
// S=8192, H=1024, NH=16, HD=64, NSEG=8, L=1024, MLP=4096.
// ---------------------------------------------------------------------------

typedef __bf16 bf16x8 __attribute__((ext_vector_type(8)));
typedef float f32x4 __attribute__((ext_vector_type(4)));
typedef float f32x16 __attribute__((ext_vector_type(16)));
typedef unsigned int u32;

__device__ __forceinline__ unsigned short f2b(float f) {  // RNE f32->bf16
  unsigned u = __float_as_uint(f);
  return (unsigned short)((u + 0x7FFFu + ((u >> 16) & 1u)) >> 16);
}
__device__ __forceinline__ float b2f(unsigned short h) {
  return __uint_as_float(((unsigned)h) << 16);
}
__device__ __forceinline__ void async_ld16(const void* g, void* l) {
  __builtin_amdgcn_global_load_lds((__attribute__((address_space(1))) void*)g,
                                   (__attribute__((address_space(3))) void*)l,
                                   16, 0, 0);
}
__device__ __forceinline__ float exp2fast(float x) {
#if __has_builtin(__builtin_amdgcn_exp2f)
  return __builtin_amdgcn_exp2f(x);
#else
  return exp2f(x);
#endif
}
__device__ __forceinline__ float rcpfast(float x) {
#if __has_builtin(__builtin_amdgcn_rcpf)
  return __builtin_amdgcn_rcpf(x);
#else
  return 1.0f / x;
#endif
}

// ---------------- fused: weight cast fp32->bf16  +  LN0 --------------------
__global__ __launch_bounds__(256) void castln_kernel(
    const float* __restrict__ w0, const float* __restrict__ w1,
    const float* __restrict__ w2, const float* __restrict__ w3,
    unsigned short* __restrict__ wdst,
    const float* __restrict__ x, const float* __restrict__ g,
    const float* __restrict__ bt, unsigned short* __restrict__ hout) {
  __shared__ float red[8];
  const int blk = blockIdx.x;
  if (blk < 12288) {
    const int t = blk * 256 + threadIdx.x;  // float4 groups
    const float* src;
    int off;
    if (t < 786432) { src = w0; off = t; }
    else if (t < 1048576) { src = w1; off = t - 786432; }
    else if (t < 2097152) { src = w2; off = t - 1048576; }
    else { src = w3; off = t - 2097152; }
    const float4 v = ((const float4*)src)[off];
    ushort4 o;
    o.x = f2b(v.x); o.y = f2b(v.y); o.z = f2b(v.z); o.w = f2b(v.w);
    ((ushort4*)wdst)[t] = o;
    return;
  }
  const int row = blk - 12288, t = threadIdx.x;
  const float4 v = ((const float4*)(x + (size_t)row * 1024))[t];
  float s = v.x + v.y + v.z + v.w;
  float s2 = v.x * v.x + v.y * v.y + v.z * v.z + v.w * v.w;
#pragma unroll
  for (int m = 1; m < 64; m <<= 1) {
    s += __shfl_xor(s, m, 64);
    s2 += __shfl_xor(s2, m, 64);
  }
  if ((t & 63) == 0) { red[t >> 6] = s; red[4 + (t >> 6)] = s2; }
  __syncthreads();
  const float ts = red[0] + red[1] + red[2] + red[3];
  const float ts2 = red[4] + red[5] + red[6] + red[7];
  const float mean = ts * (1.f / 1024.f);
  const float var = ts2 * (1.f / 1024.f) - mean * mean;
  const float inv = rsqrtf(var + 1e-5f);
  const float4 gv = ((const float4*)g)[t];
  const float4 bv = ((const float4*)bt)[t];
  ushort4 o;
  o.x = f2b((v.x - mean) * inv * gv.x + bv.x);
  o.y = f2b((v.y - mean) * inv * gv.y + bv.y);
  o.z = f2b((v.z - mean) * inv * gv.z + bv.z);
  o.w = f2b((v.w - mean) * inv * gv.w + bv.w);
  ((ushort4*)hout)[(size_t)row * 256 + t] = o;
}

// ---------------- layernorm (row of 1024) -> bf16 (standalone, LN1) --------
__global__ __launch_bounds__(256) void ln_kernel(const float* __restrict__ x,
                                                 const float* __restrict__ g,
                                                 const float* __restrict__ bt,
                                                 unsigned short* __restrict__ out) {
  __shared__ float red[8];
  const int row = blockIdx.x, t = threadIdx.x;
  const float4 v = ((const float4*)(x + (size_t)row * 1024))[t];
  float s = v.x + v.y + v.z + v.w;
  float s2 = v.x * v.x + v.y * v.y + v.z * v.z + v.w * v.w;
#pragma unroll
  for (int m = 1; m < 64; m <<= 1) {
    s += __shfl_xor(s, m, 64);
    s2 += __shfl_xor(s2, m, 64);
  }
  if ((t & 63) == 0) { red[t >> 6] = s; red[4 + (t >> 6)] = s2; }
  __syncthreads();
  const float ts = red[0] + red[1] + red[2] + red[3];
  const float ts2 = red[4] + red[5] + red[6] + red[7];
  const float mean = ts * (1.f / 1024.f);
  const float var = ts2 * (1.f / 1024.f) - mean * mean;
  const float inv = rsqrtf(var + 1e-5f);
  const float4 gv = ((const float4*)g)[t];
  const float4 bv = ((const float4*)bt)[t];
  ushort4 o;
  o.x = f2b((v.x - mean) * inv * gv.x + bv.x);
  o.y = f2b((v.y - mean) * inv * gv.y + bv.y);
  o.z = f2b((v.z - mean) * inv * gv.z + bv.z);
  o.w = f2b((v.w - mean) * inv * gv.w + bv.w);
  ((ushort4*)out)[(size_t)row * 256 + t] = o;
}

// ---------------- GEMM A (r3): BM x 256, 8-phase, 2x 32-k LDS slots --------
// MODE 1: outf = acc + res           MODE 2: outb = bf16(gelu(acc+bias))
// MODE 3: outf = acc + bias + res    MODE 4: outb = bf16(acc)
template <int MODE, int NBN, int BM>
__global__ __launch_bounds__(512, 2) void gemm_p8(
    const unsigned short* __restrict__ A, const unsigned short* __restrict__ B,
    int M, int N, int K, float* __restrict__ outf, unsigned short* __restrict__ outb,
    const float* __restrict__ res, const float* __restrict__ bias) {
  constexpr int NPH = (BM == 256) ? 4 : 2;   // phases per K-tile
  constexpr int NF = (BM == 256) ? 2 : 4;    // B frags per phase
  constexpr int M_REP = BM / 32;             // 8 | 4 (per-wave M frags)
  constexpr int AI = BM / 128;               // A stage insts per slot per wave
  constexpr int STG2 = (BM == 256) ? 2 : 1;  // phase staging k0[t+2]
  __shared__ __align__(16) unsigned short As[2][2][BM * 32];
  __shared__ __align__(16) unsigned short Bs[2][2][256 * 32];
  const int bid = blockIdx.x;
  const int j8 = bid & 7, g = bid >> 3;
  const int bm = ((g / NBN) * 8 + j8) * BM;
  const int bn = (g % NBN) * 256;
  const int t = threadIdx.x, wave = t >> 6, lane = t & 63;
  const int quad = lane >> 4, l16 = lane & 15;
  const int wm = (wave >> 2) * (M_REP * 16);
  const int wn = (wave & 3) * 64;
  const int r16 = lane >> 2;
  const int cs8 = (((lane & 3) ^ ((lane >> 3) & 3)) * 8);
  const unsigned short* AgS[AI];
  unsigned short* AlS[AI];
#pragma unroll
  for (int i = 0; i < AI; i++) {
    const int r0 = wave * (AI * 16) + i * 16;
    AgS[i] = A + (size_t)(bm + r0 + r16) * K + cs8;
    AlS[i] = &As[0][0][r0 * 32];
  }
  const unsigned short* BgS[2];
  unsigned short* BlS[2];
#pragma unroll
  for (int i = 0; i < 2; i++) {
    const int r0 = wave * 32 + i * 16;
    BgS[i] = B + (size_t)(bn + r0 + r16) * K + cs8;
    BlS[i] = &Bs[0][0][r0 * 32];
  }
#define STG(bi, kt, ks)                                                      \
  do {                                                                       \
    _Pragma("unroll") for (int i_ = 0; i_ < AI; i_++)                        \
        async_ld16(AgS[i_] + (size_t)(kt) * 64 + (ks) * 32,                  \
                   AlS[i_] + ((bi) * 2 + (ks)) * (BM * 32));                 \
    _Pragma("unroll") for (int i_ = 0; i_ < 2; i_++)                         \
        async_ld16(BgS[i_] + (size_t)(kt) * 64 + (ks) * 32,                  \
                   BlS[i_] + ((bi) * 2 + (ks)) * (256 * 32));                \
  } while (0)

  f32x4 acc[M_REP][4] = {};
  const int NT = K >> 6;
  const int rq = ((quad ^ ((l16 >> 1) & 3)) * 8);  // read-side swizzled chunk
  STG(0, 0, 0);
  STG(0, 0, 1);
  STG(1, 1, 0);
  __builtin_amdgcn_sched_barrier(0);
  if (BM == 256) asm volatile("s_waitcnt vmcnt(4)" ::: "memory");
  else           asm volatile("s_waitcnt vmcnt(3)" ::: "memory");
  __builtin_amdgcn_sched_barrier(0);
  __builtin_amdgcn_s_barrier();
  __builtin_amdgcn_sched_barrier(0);

  bf16x8 af[M_REP];
  for (int u = 0; u < NT; ++u) {
    const int buf = u & 1, nbuf = buf ^ 1;
#pragma unroll
    for (int p = 0; p < NPH; ++p) {
      const int ks = (NPH == 4) ? (p >> 1) : p;
      const int j0 = (NPH == 4) ? (p & 1) * 2 : 0;
      const unsigned short* Ab = &As[buf][ks][0];
      const unsigned short* Bb = &Bs[buf][ks][0];
      if (NPH == 2 || (p & 1) == 0) {
#pragma unroll
        for (int i = 0; i < M_REP; i++)
          af[i] = *(const bf16x8*)(Ab + (wm + i * 16 + l16) * 32 + rq);
      }
      bf16x8 bfv[NF];
#pragma unroll
      for (int jj = 0; jj < NF; jj++)
        bfv[jj] = *(const bf16x8*)(Bb + (wn + (j0 + jj) * 16 + l16) * 32 + rq);
      if (p == 0 && u + 1 < NT) STG(nbuf, u + 1, 1);        // k1 of t+1
      if (p == STG2 && u + 2 < NT) STG(buf, u + 2, 0);      // k0 of t+2
      __builtin_amdgcn_sched_barrier(0);
      __builtin_amdgcn_s_barrier();
      asm volatile("s_waitcnt lgkmcnt(0)" ::: "memory");
      __builtin_amdgcn_sched_barrier(0);
      __builtin_amdgcn_s_setprio(1);
#pragma unroll
      for (int jj = 0; jj < NF; jj++)
#pragma unroll
        for (int i = 0; i < M_REP; i++)
          acc[i][j0 + jj] = __builtin_amdgcn_mfma_f32_16x16x32_bf16(
              af[i], bfv[jj], acc[i][j0 + jj], 0, 0, 0);
      __builtin_amdgcn_s_setprio(0);
      if (p == NPH - 1 && u + 1 < NT) {  // tile-end counted wait
        __builtin_amdgcn_sched_barrier(0);
        if (u + 2 < NT) {
          if (BM == 256) asm volatile("s_waitcnt vmcnt(4)" ::: "memory");
          else           asm volatile("s_waitcnt vmcnt(3)" ::: "memory");
        } else {
          asm volatile("s_waitcnt vmcnt(0)" ::: "memory");
        }
      }
      __builtin_amdgcn_sched_barrier(0);
      __builtin_amdgcn_s_barrier();
      __builtin_amdgcn_sched_barrier(0);
    }
  }
#undef STG
#pragma unroll
  for (int i = 0; i < M_REP; i++)
#pragma unroll
    for (int jj = 0; jj < 4; jj++)
#pragma unroll
      for (int r = 0; r < 4; r++) {
        const int m = bm + wm + i * 16 + quad * 4 + r;
        const int n = bn + wn + jj * 16 + l16;
        const size_t idx = (size_t)m * N + n;
        const float v = acc[i][jj][r];
        if (MODE == 1) {
          outf[idx] = v + res[idx];
        } else if (MODE == 2) {
          const float z = v + bias[n];
          const float u = z * (0.7978845608f + 0.03567740814f * z * z);
          const float e = fminf(u * 2.885390082f, 80.f);
          const float tt = exp2fast(e);
          outb[idx] = f2b(z * tt * rcpfast(tt + 1.0f));
        } else if (MODE == 3) {
          outf[idx] = v + bias[n] + res[idx];
        } else {  // MODE 4
          outb[idx] = f2b(v);
        }
      }
}

// ---------------- GEMM B (r2): 256xBN, BK=64, 2-phase counted pipeline -----
template <int MODE, int NBN, int BN>
__global__ __launch_bounds__(512, 2) void gemm_bt8(
    const unsigned short* __restrict__ A, const unsigned short* __restrict__ B,
    int M, int N, int K, float* __restrict__ outf, unsigned short* __restrict__ outb,
    const float* __restrict__ res, const float* __restrict__ bias) {
  constexpr int NBI = BN / 64;             // B staging insts per wave (2|4)
  constexpr int WN_WAVES = BN / 64;        // waves tiling N (2|4)
  constexpr int WM_WAVES = 8 / WN_WAVES;   // waves tiling M (4|2)
  constexpr int M_REP = (256 / WM_WAVES) / 16;  // 4|8
  constexpr int N_REP = 4;
  __shared__ __align__(16) unsigned short As[2][256 * 64];
  __shared__ __align__(16) unsigned short Bs[2][BN * 64];
  const int bid = blockIdx.x;
  const int j8 = bid & 7, g = bid >> 3;
  const int bm = ((g / NBN) * 8 + j8) * 256;
  const int bn = (g % NBN) * BN;
  const int t = threadIdx.x, wave = t >> 6, lane = t & 63;
  const int quad = lane >> 4, l16 = lane & 15;
  const int wm = (wave / WN_WAVES) * (M_REP * 16);
  const int wn = (wave % WN_WAVES) * 64;
  const int l8 = lane >> 3;
  const int cs = ((lane & 7) ^ (l8 & 7)) * 8;
  const unsigned short* Ag[4];
  unsigned short* Al[4];
#pragma unroll
  for (int i = 0; i < 4; i++) {
    const int r = wave * 32 + i * 8;
    Ag[i] = A + (size_t)(bm + r + l8) * K + cs;
    Al[i] = &As[0][r * 64];
  }
  const unsigned short* Bg[NBI];
  unsigned short* Bl[NBI];
#pragma unroll
  for (int i = 0; i < NBI; i++) {
    const int r = wave * (NBI * 8) + i * 8;
    Bg[i] = B + (size_t)(bn + r + l8) * K + cs;
    Bl[i] = &Bs[0][r * 64];
  }
#define STAGE(bi, k0)                                                        \
  do {                                                                       \
    _Pragma("unroll") for (int i_ = 0; i_ < 4; i_++)                         \
        async_ld16(Ag[i_] + (k0), Al[i_] + (bi) * (256 * 64));               \
    _Pragma("unroll") for (int i_ = 0; i_ < NBI; i_++)                       \
        async_ld16(Bg[i_] + (k0), Bl[i_] + (bi) * (BN * 64));                \
  } while (0)

  f32x4 acc[M_REP][N_REP] = {};
  const int NT = K >> 6;
  const int swk = l16 & 7;  // ds_read swizzle key (= row&7 for frag rows)
  STAGE(0, 0);
  STAGE(1, 64);
  if (BN == 256) asm volatile("s_waitcnt vmcnt(8)" ::: "memory");
  else           asm volatile("s_waitcnt vmcnt(6)" ::: "memory");
  __builtin_amdgcn_sched_barrier(0);
  __builtin_amdgcn_s_barrier();
  __builtin_amdgcn_sched_barrier(0);
  int k0 = 128;
  for (int tI = 0; tI < NT; ++tI) {
    const int cur = tI & 1;
    const unsigned short* Ab = &As[cur][0];
    const unsigned short* Bb = &Bs[cur][0];
#pragma unroll
    for (int ks = 0; ks < 2; ks++) {
      bf16x8 af[M_REP], bfv[N_REP];
#pragma unroll
      for (int i = 0; i < M_REP; i++)
        af[i] = *(const bf16x8*)(Ab + (wm + i * 16 + l16) * 64 +
                                 (((ks * 4 + quad) ^ swk) * 8));
#pragma unroll
      for (int j = 0; j < N_REP; j++)
        bfv[j] = *(const bf16x8*)(Bb + (wn + j * 16 + l16) * 64 +
                                  (((ks * 4 + quad) ^ swk) * 8));
      __builtin_amdgcn_s_setprio(1);
#pragma unroll
      for (int j = 0; j < N_REP; j++)
#pragma unroll
        for (int i = 0; i < M_REP; i++)
          acc[i][j] = __builtin_amdgcn_mfma_f32_16x16x32_bf16(af[i], bfv[j],
                                                              acc[i][j], 0, 0, 0);
      __builtin_amdgcn_s_setprio(0);
    }
    if (tI + 1 == NT) break;
    __builtin_amdgcn_sched_barrier(0);
    __builtin_amdgcn_s_barrier();  // all waves done reading buf[cur]
    __builtin_amdgcn_sched_barrier(0);
    if (tI + 2 < NT) {
      STAGE(cur, k0);              // overwrite buf[cur] with tile tI+2
      k0 += 64;
      if (BN == 256) asm volatile("s_waitcnt vmcnt(8)" ::: "memory");
      else           asm volatile("s_waitcnt vmcnt(6)" ::: "memory");
    } else {
      asm volatile("s_waitcnt vmcnt(0)" ::: "memory");
    }
    __builtin_amdgcn_sched_barrier(0);
    __builtin_amdgcn_s_barrier();  // all waves' next tile resident
    __builtin_amdgcn_sched_barrier(0);
  }
#undef STAGE
#pragma unroll
  for (int i = 0; i < M_REP; i++)
#pragma unroll
    for (int j = 0; j < N_REP; j++)
#pragma unroll
      for (int r = 0; r < 4; r++) {
        const int m = bm + wm + i * 16 + quad * 4 + r;
        const int n = bn + wn + j * 16 + l16;
        const size_t idx = (size_t)m * N + n;
        const float v = acc[i][j][r];
        if (MODE == 1) {
          outf[idx] = v + res[idx];
        } else if (MODE == 2) {
          const float z = v + bias[n];
          const float u = z * (0.7978845608f + 0.03567740814f * z * z);
          const float e = fminf(u * 2.885390082f, 80.f);
          const float tt = exp2fast(e);
          outb[idx] = f2b(z * tt * rcpfast(tt + 1.0f));
        } else if (MODE == 3) {
          outf[idx] = v + bias[n] + res[idx];
        } else {  // MODE 4
          outb[idx] = f2b(v);
        }
      }
}

// ---------------- DIAGNOSTIC: staging-only skeleton of gemm_bt8 ------------
// Identical LDS layout, STAGE pattern, counted vmcnt(8), raw-barrier rhythm;
// ds_read/MFMA deleted. 3 K-sweeps (k0 wraps mod K). Measures the pure
// staging-delivery floor of the bt8 structure at FC0 shape.
__global__ __launch_bounds__(512, 2) void abl_stage(
    const unsigned short* __restrict__ A, const unsigned short* __restrict__ B,
    int M, int N, int K, unsigned short* __restrict__ scratch) {
  constexpr int NBN = 16;
  __shared__ __align__(16) unsigned short As[2][256 * 64];
  __shared__ __align__(16) unsigned short Bs[2][256 * 64];
  const int bid = blockIdx.x;
  const int j8 = bid & 7, g = bid >> 3;
  const int bm = ((g / NBN) * 8 + j8) * 256;
  const int bn = (g % NBN) * 256;
  const int t = threadIdx.x, wave = t >> 6, lane = t & 63;
  const int l8 = lane >> 3;
  const int cs = ((lane & 7) ^ (l8 & 7)) * 8;
  const unsigned short* Ag[4];
  unsigned short* Al[4];
#pragma unroll
  for (int i = 0; i < 4; i++) {
    const int r = wave * 32 + i * 8;
    Ag[i] = A + (size_t)(bm + r + l8) * K + cs;
    Al[i] = &As[0][r * 64];
  }
  const unsigned short* Bg[4];
  unsigned short* Bl[4];
#pragma unroll
  for (int i = 0; i < 4; i++) {
    const int r = wave * 32 + i * 8;
    Bg[i] = B + (size_t)(bn + r + l8) * K + cs;
    Bl[i] = &Bs[0][r * 64];
  }
#define STAGE(bi, k0)                                                        \
  do {                                                                       \
    _Pragma("unroll") for (int i_ = 0; i_ < 4; i_++)                         \
        async_ld16(Ag[i_] + (k0), Al[i_] + (bi) * (256 * 64));               \
    _Pragma("unroll") for (int i_ = 0; i_ < 4; i_++)                         \
        async_ld16(Bg[i_] + (k0), Bl[i_] + (bi) * (256 * 64));               \
  } while (0)
  const int NT = (K >> 6) * 3;  // 3 sweeps of the K range
  STAGE(0, 0);
  STAGE(1, 64);
  asm volatile("s_waitcnt vmcnt(8)" ::: "memory");
  __builtin_amdgcn_sched_barrier(0);
  __builtin_amdgcn_s_barrier();
  __builtin_amdgcn_sched_barrier(0);
  int k0 = 128;
  if (k0 >= K) k0 = 0;
  for (int tI = 0; tI < NT; ++tI) {
    const int cur = tI & 1;
    // (ds_read + MFMA phase deleted — this is the staging floor)
    if (tI + 1 == NT) break;
    __builtin_amdgcn_sched_barrier(0);
    __builtin_amdgcn_s_barrier();
    __builtin_amdgcn_sched_barrier(0);
    if (tI + 2 < NT) {
      STAGE(cur, k0);
      k0 += 64;
      if (k0 >= K) k0 = 0;
      asm volatile("s_waitcnt vmcnt(8)" ::: "memory");
    } else {
      asm volatile("s_waitcnt vmcnt(0)" ::: "memory");
    }
    __builtin_amdgcn_sched_barrier(0);
    __builtin_amdgcn_s_barrier();
    __builtin_amdgcn_sched_barrier(0);
  }
#undef STAGE
  asm volatile("s_waitcnt vmcnt(0) lgkmcnt(0)" ::: "memory");
  __syncthreads();
  // consume LDS so nothing is removable; write to dead scratch
  scratch[(size_t)bid * 512 + t] =
      As[0][t] ^ As[1][t] ^ Bs[0][t] ^ Bs[1][t];
}

// ---------------- fused RoPE + V-transpose ---------------------------------
__device__ __forceinline__ u32 rope2(u32 in, float c, float sn, float sc) {
  const float a = b2f((unsigned short)(in & 0xffff));
  const float b = b2f((unsigned short)(in >> 16));
  return (u32)f2b((a * c - b * sn) * sc) | ((u32)f2b((a * sn + b * c) * sc) << 16);
}
__global__ __launch_bounds__(256) void ropevt_kernel(const unsigned short* __restrict__ qkv,
                                                     const float* __restrict__ cb,
                                                     const float* __restrict__ sb,
                                                     unsigned short* __restrict__ qh,
                                                     unsigned short* __restrict__ kh,
                                                     unsigned short* __restrict__ vt) {
  __shared__ unsigned short tile[64][72];
  const int blk = blockIdx.x;
  if (blk < 4096) {
    const int tid = blk * 256 + threadIdx.x;  // S*NH*8 threads
    const int ii = tid & 7, head = (tid >> 3) & 15, s = tid >> 7;
    const float4 cv = *(const float4*)(cb + s * 32 + ii * 4);
    const float4 sv = *(const float4*)(sb + s * 32 + ii * 4);
    const unsigned short* base = qkv + (size_t)s * 3072 + head * 64 + ii * 8;
    const uint4 qa = *(const uint4*)base;
    const uint4 ka = *(const uint4*)(base + 1024);
    const int seg = s >> 10, l = s & 1023;
    const size_t o = ((size_t)((seg * 16 + head) * 1024 + l)) * 64 + ii * 8;
    const float QSC = 0.125f * 1.44269504f;
    uint4 qo, ko;
    qo.x = rope2(qa.x, cv.x, sv.x, QSC); ko.x = rope2(ka.x, cv.x, sv.x, 1.f);
    qo.y = rope2(qa.y, cv.y, sv.y, QSC); ko.y = rope2(ka.y, cv.y, sv.y, 1.f);
    qo.z = rope2(qa.z, cv.z, sv.z, QSC); ko.z = rope2(ka.z, cv.z, sv.z, 1.f);
    qo.w = rope2(qa.w, cv.w, sv.w, QSC); ko.w = rope2(ka.w, cv.w, sv.w, 1.f);
    *(uint4*)(qh + o) = qo;
    *(uint4*)(kh + o) = ko;
    return;
  }
  const int b = blk - 4096;  // 8*16*16
  const int lt = b & 15, head = (b >> 4) & 15, seg = b >> 8;
  const int t = threadIdx.x;
  const int r = t >> 2, c0 = (t & 3) * 16;
  const unsigned short* src =
      qkv + ((size_t)(seg * 1024 + lt * 64 + r)) * 3072 + 2048 + head * 64 + c0;
#pragma unroll
  for (int k = 0; k < 16; k++) tile[r][c0 + k] = src[k];
  __syncthreads();
  unsigned short* dst =
      vt + ((size_t)((seg * 16 + head) * 64 + r)) * 1024 + lt * 64 + c0;
#pragma unroll
  for (int k = 0; k < 16; k++) dst[k] = tile[c0 + k][r];
}

// ---------------- flash attention, 32x32x16 MFMA, in-register P ------------
__global__ __launch_bounds__(256) void attn_kernel(const unsigned short* __restrict__ qh,
                                                   const unsigned short* __restrict__ kh,
                                                   const unsigned short* __restrict__ vt,
                                                   unsigned short* __restrict__ out) {
  __shared__ __align__(16) unsigned short Qs[128 * 64];
  __shared__ __align__(16) unsigned short Ks[64 * 64];
  __shared__ __align__(16) unsigned short Vs[64 * 64];  // [hd][key]
  __shared__ float wl[128];
  const int b = blockIdx.x;
  const int head = b & 15, seg = (b >> 4) & 7, qt = b >> 7;
  const int t = threadIdx.x, wave = t >> 6, lane = t & 63;
  const int h = lane >> 5, q31 = lane & 31;
  const size_t sh = (size_t)(seg * 16 + head);
  const unsigned short* qbase = qh + (sh * 1024 + (size_t)qt * 128) * 64;
  const unsigned short* kbase = kh + sh * 1024 * 64;
  const unsigned short* vbase = vt + sh * 64 * 1024;
  const int r8 = lane >> 3;
  const int c8 = ((lane & 7) ^ (r8 & 7)) * 8;  // swizzled source col (shorts)
#pragma unroll
  for (int cc = 0; cc < 4; cc++) {  // stage Q once (16KB, 16 chunks)
    const int chunk = wave * 4 + cc;
    async_ld16(qbase + (size_t)(chunk * 8 + r8) * 64 + c8, Qs + chunk * 512);
  }
  const int qrow_l = wave * 32 + q31;          // this lane's query row in tile
  const int qsw = qrow_l & 7;                  // Qs swizzle key
  bf16x8 qf[4];                                // Q B-frags, loaded once
  float lsum = 0.f;
  f32x16 oacc[2] = {};

  for (int kt = 0; kt < 16; kt++) {
    const int ch0 = wave * 2;
    async_ld16(kbase + (size_t)(kt * 64 + ch0 * 8 + r8) * 64 + c8, Ks + ch0 * 512);
    async_ld16(kbase + (size_t)(kt * 64 + ch0 * 8 + 8 + r8) * 64 + c8, Ks + ch0 * 512 + 512);
    async_ld16(vbase + (size_t)(ch0 * 8 + r8) * 1024 + kt * 64 + c8, Vs + ch0 * 512);
    async_ld16(vbase + (size_t)(ch0 * 8 + 8 + r8) * 1024 + kt * 64 + c8, Vs + ch0 * 512 + 512);
    __syncthreads();
    if (kt == 0) {
#pragma unroll
      for (int ks = 0; ks < 4; ks++)
        qf[ks] = *(const bf16x8*)(Qs + qrow_l * 64 + (((2 * ks + h) ^ qsw)) * 8);
    }
    // S^T = K.Q^T : 2 key tiles x 4 ksteps
    f32x16 st[2] = {{}, {}};
#pragma unroll
    for (int T = 0; T < 2; T++) {
      const int krow = 32 * T + q31;
      const int ksw = krow & 7;
#pragma unroll
      for (int ks = 0; ks < 4; ks++) {
        const bf16x8 kf = *(const bf16x8*)(Ks + krow * 64 + (((2 * ks + h) ^ ksw)) * 8);
        st[T] = __builtin_amdgcn_mfma_f32_32x32x16_bf16(kf, qf[ks], st[T], 0, 0, 0);
      }
    }
    // p = exp2(s) (q pre-scaled by log2e/8); pack bf16 pairs per group
    u32 pk[2][4][2];
#pragma unroll
    for (int T = 0; T < 2; T++)
#pragma unroll
      for (int g = 0; g < 4; g++)
#pragma unroll
        for (int e = 0; e < 2; e++) {
          const float plo = exp2fast(st[T][4 * g + 2 * e]);
          const float phi = exp2fast(st[T][4 * g + 2 * e + 1]);
          lsum += plo + phi;
          pk[T][g][e] = (u32)f2b(plo) | ((u32)f2b(phi) << 16);
        }
    // half-wave exchange of the cross quads
    u32 rcv[2][4];
#pragma unroll
    for (int T = 0; T < 2; T++) {
      const u32 p0 = h ? pk[T][0][0] : pk[T][1][0];
      const u32 p1 = h ? pk[T][0][1] : pk[T][1][1];
      const u32 p2 = h ? pk[T][2][0] : pk[T][3][0];
      const u32 p3 = h ? pk[T][2][1] : pk[T][3][1];
      rcv[T][0] = (u32)__shfl_xor((int)p0, 32, 64);
      rcv[T][1] = (u32)__shfl_xor((int)p1, 32, 64);
      rcv[T][2] = (u32)__shfl_xor((int)p2, 32, 64);
      rcv[T][3] = (u32)__shfl_xor((int)p3, 32, 64);
    }
    // O += P.V
#pragma unroll
    for (int tt = 0; tt < 4; tt++) {
      const int T = tt >> 1, uu = tt & 1;
      union { u32 u[4]; bf16x8 v; } af;
      if (h == 0) {
        af.u[0] = pk[T][2 * uu][0];
        af.u[1] = pk[T][2 * uu][1];
        af.u[2] = rcv[T][2 * uu];
        af.u[3] = rcv[T][2 * uu + 1];
      } else {
        af.u[0] = rcv[T][2 * uu];
        af.u[1] = rcv[T][2 * uu + 1];
        af.u[2] = pk[T][2 * uu + 1][0];
        af.u[3] = pk[T][2 * uu + 1][1];
      }
#pragma unroll
      for (int ot = 0; ot < 2; ot++) {
        const int vrow = 32 * ot + q31;
        const int vsw = vrow & 7;
        const bf16x8 bv = *(const bf16x8*)(Vs + vrow * 64 + (((2 * tt + h) ^ vsw)) * 8);
        oacc[ot] = __builtin_amdgcn_mfma_f32_32x32x16_bf16(af.v, bv, oacc[ot], 0, 0, 0);
      }
    }
    __syncthreads();
  }
  // epilogue: full row-sum, normalize, store
  lsum += __shfl_xor(lsum, 32, 64);
  if (h == 0) wl[wave * 32 + q31] = lsum;
  const int qglob = seg * 1024 + qt * 128 + wave * 32;
#pragma unroll
  for (int g = 0; g < 4; g++) {
    const float4 lv = *(const float4*)&wl[wave * 32 + 8 * g + 4 * h];
#pragma unroll
    for (int m = 0; m < 4; m++) {
      const int r16 = 4 * g + m;
      const int qrow = qglob + m + 8 * g + 4 * h;
      const float invl = rcpfast((&lv.x)[m]);
#pragma unroll
      for (int ot = 0; ot < 2; ot++)
        out[(size_t)qrow * 1024 + head * 64 + 32 * ot + q31] = f2b(oacc[ot][r16] * invl);
    }
  }
}

// ---------------------------------------------------------------------------
extern "C" void kernel_launch(void* const* d_in, const int* in_sizes, int n_in,
                              void* d_out, int out_size, void* d_ws, size_t ws_size,
                              hipStream_t stream) {
  (void)in_sizes; (void)n_in; (void)out_size; (void)ws_size;
  const float* x    = (const float*)d_in[0];
  const float* wqkv = (const float*)d_in[1];
  const float* wo   = (const float*)d_in[2];
  const float* ln0g = (const float*)d_in[3];
  const float* ln0b = (const float*)d_in[4];
  const float* ln1g = (const float*)d_in[5];
  const float* ln1b = (const float*)d_in[6];
  const float* fc0w = (const float*)d_in[7];
  const float* fc0b = (const float*)d_in[8];
  const float* fc1w = (const float*)d_in[9];
  const float* fc1b = (const float*)d_in[10];
  const float* rc   = (const float*)d_in[11];
  const float* rsn  = (const float*)d_in[12];
  float* out = (float*)d_out;
  char* w = (char*)d_ws;
  const size_t MB = 1u << 20;
  unsigned short* hb    = (unsigned short*)(w + 0);
  unsigned short* bqkv  = (unsigned short*)(w + 16 * MB);
  unsigned short* bwo   = (unsigned short*)(w + 22 * MB);
  unsigned short* bfc0  = (unsigned short*)(w + 24 * MB);
  unsigned short* bfc1  = (unsigned short*)(w + 32 * MB);
  unsigned short* qhb   = (unsigned short*)(w + 40 * MB);
  unsigned short* khb   = (unsigned short*)(w + 56 * MB);
  unsigned short* vtb   = (unsigned short*)(w + 72 * MB);
  unsigned short* attnb = (unsigned short*)(w + 88 * MB);
  unsigned short* qkvb  = (unsigned short*)(w + 104 * MB);
  unsigned short* midb  = (unsigned short*)(w + 104 * MB);  // alias, qkvb dead

  // 1: weight casts + LN0 (one dispatch)
  castln_kernel<<<20480, 256, 0, stream>>>(wqkv, wo, fc0w, fc1w, bqkv,
                                           x, ln0g, ln0b, hb);
  // 2: QKV = hb @ wqkv^T   (p8, 256x256, 384 blk = 1.5/CU)
  gemm_p8<4, 12, 256><<<384, 512, 0, stream>>>(hb, bqkv, 8192, 3072, 1024,
                                               nullptr, qkvb, nullptr, nullptr);
  // 3: RoPE + V-transpose (one dispatch)
  ropevt_kernel<<<6144, 256, 0, stream>>>(qkvb, rc, rsn, qhb, khb, vtb);
  // 4: attention
  attn_kernel<<<1024, 256, 0, stream>>>(qhb, khb, vtb, attnb);
  // 5: WO: out = attn @ wo^T + x   (p8, 128x256, 256 blk = 1.0/CU)
  gemm_p8<1, 4, 128><<<256, 512, 0, stream>>>(attnb, bwo, 8192, 1024, 1024,
                                              out, nullptr, x, nullptr);
  // 6: LN1
  ln_kernel<<<8192, 256, 0, stream>>>(out, ln1g, ln1b, hb);
  // 7: FC0 (+bias, GELU) -> midb   (bt8, 256x256, 512 blk = 2.0/CU)
  gemm_bt8<2, 16, 256><<<512, 512, 0, stream>>>(hb, bfc0, 8192, 4096, 1024,
                                                nullptr, midb, nullptr, fc0b);
  // 8: FC1: out = mid @ fc1^T + bias + out   (p8, 128x256, 256 blk, K=4096)
  gemm_p8<3, 4, 128><<<256, 512, 0, stream>>>(midb, bfc1, 8192, 1024, 4096,
                                              out, nullptr, out, fc1b);
  // 9: DIAGNOSTIC (after all real work; writes dead scratch at w+40MB):
  //    staging-only skeleton of FC0's bt8, 3 K-sweeps.
  abl_stage<<<512, 512, 0, stream>>>(hb, bfc0, 8192, 4096, 1024,
                                     (unsigned short*)(w + 40 * MB));
}

// Round 10
// 550.780 us; speedup vs baseline: 1.0047x; 1.0047x over previous
//
#include <hip/hip_runtime.h>
#include <math.h>

// ---------------------------------------------------------------------------
// VideoChat3 vision encoder block, bf16-MFMA pipeline. Round 17:
//  - r9 DIAGNOSTIC READOUT: abl_stage (3 FC0 staging sweeps) absent from
//    top-5 => staging floor <=30us/sweep = 27% of FC0's 113us = exactly the
//    L2-BW floor (1GB @ 34.5TB/s = 29us). MFMA floor ~32us. No phase
//    dominates: the cost is the all-waves-wait-on-one-barrier convoy.
//  - NEW: gemm_pw = BARRIER-FREE GEMM. 128^2 tile, 4 waves; each wave
//    stages its own private 64 A-rows + 64 B-rows (dbuf, 16KB/wave, 64KB
//    block -> 2 blk/CU). No cross-wave LDS sharing => zero s_barrier in
//    the K-loop. Per iter: ds_read own buf -> lgkm(0) (buf free) -> stage
//    tt+2 into it -> MFMA -> counted vmcnt(8) on OWN loads (vmcnt is
//    per-wave). Waves drift freely; stragglers stall one wave, not the CU.
//    Cost: 2x staging duplication (dup hits L2; HBM FETCH unchanged).
//  - Experiment: FC0 only (A/B vs r8's 113us). FC1/QKV/WO stay p8 (FC1-p8
//    measured 92us = 747 TF, best rate). abl_stage + dead bt8 removed.
// S=8192, H=1024, NH=16, HD=64, NSEG=8, L=1024, MLP=4096.
// ---------------------------------------------------------------------------

typedef __bf16 bf16x8 __attribute__((ext_vector_type(8)));
typedef float f32x4 __attribute__((ext_vector_type(4)));
typedef float f32x16 __attribute__((ext_vector_type(16)));
typedef unsigned int u32;

__device__ __forceinline__ unsigned short f2b(float f) {  // RNE f32->bf16
  unsigned u = __float_as_uint(f);
  return (unsigned short)((u + 0x7FFFu + ((u >> 16) & 1u)) >> 16);
}
__device__ __forceinline__ float b2f(unsigned short h) {
  return __uint_as_float(((unsigned)h) << 16);
}
__device__ __forceinline__ void async_ld16(const void* g, void* l) {
  __builtin_amdgcn_global_load_lds((__attribute__((address_space(1))) void*)g,
                                   (__attribute__((address_space(3))) void*)l,
                                   16, 0, 0);
}
__device__ __forceinline__ float exp2fast(float x) {
#if __has_builtin(__builtin_amdgcn_exp2f)
  return __builtin_amdgcn_exp2f(x);
#else
  return exp2f(x);
#endif
}
__device__ __forceinline__ float rcpfast(float x) {
#if __has_builtin(__builtin_amdgcn_rcpf)
  return __builtin_amdgcn_rcpf(x);
#else
  return 1.0f / x;
#endif
}

// ---------------- fused: weight cast fp32->bf16  +  LN0 --------------------
__global__ __launch_bounds__(256) void castln_kernel(
    const float* __restrict__ w0, const float* __restrict__ w1,
    const float* __restrict__ w2, const float* __restrict__ w3,
    unsigned short* __restrict__ wdst,
    const float* __restrict__ x, const float* __restrict__ g,
    const float* __restrict__ bt, unsigned short* __restrict__ hout) {
  __shared__ float red[8];
  const int blk = blockIdx.x;
  if (blk < 12288) {
    const int t = blk * 256 + threadIdx.x;  // float4 groups
    const float* src;
    int off;
    if (t < 786432) { src = w0; off = t; }
    else if (t < 1048576) { src = w1; off = t - 786432; }
    else if (t < 2097152) { src = w2; off = t - 1048576; }
    else { src = w3; off = t - 2097152; }
    const float4 v = ((const float4*)src)[off];
    ushort4 o;
    o.x = f2b(v.x); o.y = f2b(v.y); o.z = f2b(v.z); o.w = f2b(v.w);
    ((ushort4*)wdst)[t] = o;
    return;
  }
  const int row = blk - 12288, t = threadIdx.x;
  const float4 v = ((const float4*)(x + (size_t)row * 1024))[t];
  float s = v.x + v.y + v.z + v.w;
  float s2 = v.x * v.x + v.y * v.y + v.z * v.z + v.w * v.w;
#pragma unroll
  for (int m = 1; m < 64; m <<= 1) {
    s += __shfl_xor(s, m, 64);
    s2 += __shfl_xor(s2, m, 64);
  }
  if ((t & 63) == 0) { red[t >> 6] = s; red[4 + (t >> 6)] = s2; }
  __syncthreads();
  const float ts = red[0] + red[1] + red[2] + red[3];
  const float ts2 = red[4] + red[5] + red[6] + red[7];
  const float mean = ts * (1.f / 1024.f);
  const float var = ts2 * (1.f / 1024.f) - mean * mean;
  const float inv = rsqrtf(var + 1e-5f);
  const float4 gv = ((const float4*)g)[t];
  const float4 bv = ((const float4*)bt)[t];
  ushort4 o;
  o.x = f2b((v.x - mean) * inv * gv.x + bv.x);
  o.y = f2b((v.y - mean) * inv * gv.y + bv.y);
  o.z = f2b((v.z - mean) * inv * gv.z + bv.z);
  o.w = f2b((v.w - mean) * inv * gv.w + bv.w);
  ((ushort4*)hout)[(size_t)row * 256 + t] = o;
}

// ---------------- layernorm (row of 1024) -> bf16 (standalone, LN1) --------
__global__ __launch_bounds__(256) void ln_kernel(const float* __restrict__ x,
                                                 const float* __restrict__ g,
                                                 const float* __restrict__ bt,
                                                 unsigned short* __restrict__ out) {
  __shared__ float red[8];
  const int row = blockIdx.x, t = threadIdx.x;
  const float4 v = ((const float4*)(x + (size_t)row * 1024))[t];
  float s = v.x + v.y + v.z + v.w;
  float s2 = v.x * v.x + v.y * v.y + v.z * v.z + v.w * v.w;
#pragma unroll
  for (int m = 1; m < 64; m <<= 1) {
    s += __shfl_xor(s, m, 64);
    s2 += __shfl_xor(s2, m, 64);
  }
  if ((t & 63) == 0) { red[t >> 6] = s; red[4 + (t >> 6)] = s2; }
  __syncthreads();
  const float ts = red[0] + red[1] + red[2] + red[3];
  const float ts2 = red[4] + red[5] + red[6] + red[7];
  const float mean = ts * (1.f / 1024.f);
  const float var = ts2 * (1.f / 1024.f) - mean * mean;
  const float inv = rsqrtf(var + 1e-5f);
  const float4 gv = ((const float4*)g)[t];
  const float4 bv = ((const float4*)bt)[t];
  ushort4 o;
  o.x = f2b((v.x - mean) * inv * gv.x + bv.x);
  o.y = f2b((v.y - mean) * inv * gv.y + bv.y);
  o.z = f2b((v.z - mean) * inv * gv.z + bv.z);
  o.w = f2b((v.w - mean) * inv * gv.w + bv.w);
  ((ushort4*)out)[(size_t)row * 256 + t] = o;
}

// ---------------- GEMM A (r3): BM x 256, 8-phase, 2x 32-k LDS slots --------
// MODE 1: outf = acc + res           MODE 2: outb = bf16(gelu(acc+bias))
// MODE 3: outf = acc + bias + res    MODE 4: outb = bf16(acc)
template <int MODE, int NBN, int BM>
__global__ __launch_bounds__(512, 2) void gemm_p8(
    const unsigned short* __restrict__ A, const unsigned short* __restrict__ B,
    int M, int N, int K, float* __restrict__ outf, unsigned short* __restrict__ outb,
    const float* __restrict__ res, const float* __restrict__ bias) {
  constexpr int NPH = (BM == 256) ? 4 : 2;   // phases per K-tile
  constexpr int NF = (BM == 256) ? 2 : 4;    // B frags per phase
  constexpr int M_REP = BM / 32;             // 8 | 4 (per-wave M frags)
  constexpr int AI = BM / 128;               // A stage insts per slot per wave
  constexpr int STG2 = (BM == 256) ? 2 : 1;  // phase staging k0[t+2]
  __shared__ __align__(16) unsigned short As[2][2][BM * 32];
  __shared__ __align__(16) unsigned short Bs[2][2][256 * 32];
  const int bid = blockIdx.x;
  const int j8 = bid & 7, g = bid >> 3;
  const int bm = ((g / NBN) * 8 + j8) * BM;
  const int bn = (g % NBN) * 256;
  const int t = threadIdx.x, wave = t >> 6, lane = t & 63;
  const int quad = lane >> 4, l16 = lane & 15;
  const int wm = (wave >> 2) * (M_REP * 16);
  const int wn = (wave & 3) * 64;
  const int r16 = lane >> 2;
  const int cs8 = (((lane & 3) ^ ((lane >> 3) & 3)) * 8);
  const unsigned short* AgS[AI];
  unsigned short* AlS[AI];
#pragma unroll
  for (int i = 0; i < AI; i++) {
    const int r0 = wave * (AI * 16) + i * 16;
    AgS[i] = A + (size_t)(bm + r0 + r16) * K + cs8;
    AlS[i] = &As[0][0][r0 * 32];
  }
  const unsigned short* BgS[2];
  unsigned short* BlS[2];
#pragma unroll
  for (int i = 0; i < 2; i++) {
    const int r0 = wave * 32 + i * 16;
    BgS[i] = B + (size_t)(bn + r0 + r16) * K + cs8;
    BlS[i] = &Bs[0][0][r0 * 32];
  }
#define STG(bi, kt, ks)                                                      \
  do {                                                                       \
    _Pragma("unroll") for (int i_ = 0; i_ < AI; i_++)                        \
        async_ld16(AgS[i_] + (size_t)(kt) * 64 + (ks) * 32,                  \
                   AlS[i_] + ((bi) * 2 + (ks)) * (BM * 32));                 \
    _Pragma("unroll") for (int i_ = 0; i_ < 2; i_++)                         \
        async_ld16(BgS[i_] + (size_t)(kt) * 64 + (ks) * 32,                  \
                   BlS[i_] + ((bi) * 2 + (ks)) * (256 * 32));                \
  } while (0)

  f32x4 acc[M_REP][4] = {};
  const int NT = K >> 6;
  const int rq = ((quad ^ ((l16 >> 1) & 3)) * 8);  // read-side swizzled chunk
  STG(0, 0, 0);
  STG(0, 0, 1);
  STG(1, 1, 0);
  __builtin_amdgcn_sched_barrier(0);
  if (BM == 256) asm volatile("s_waitcnt vmcnt(4)" ::: "memory");
  else           asm volatile("s_waitcnt vmcnt(3)" ::: "memory");
  __builtin_amdgcn_sched_barrier(0);
  __builtin_amdgcn_s_barrier();
  __builtin_amdgcn_sched_barrier(0);

  bf16x8 af[M_REP];
  for (int u = 0; u < NT; ++u) {
    const int buf = u & 1, nbuf = buf ^ 1;
#pragma unroll
    for (int p = 0; p < NPH; ++p) {
      const int ks = (NPH == 4) ? (p >> 1) : p;
      const int j0 = (NPH == 4) ? (p & 1) * 2 : 0;
      const unsigned short* Ab = &As[buf][ks][0];
      const unsigned short* Bb = &Bs[buf][ks][0];
      if (NPH == 2 || (p & 1) == 0) {
#pragma unroll
        for (int i = 0; i < M_REP; i++)
          af[i] = *(const bf16x8*)(Ab + (wm + i * 16 + l16) * 32 + rq);
      }
      bf16x8 bfv[NF];
#pragma unroll
      for (int jj = 0; jj < NF; jj++)
        bfv[jj] = *(const bf16x8*)(Bb + (wn + (j0 + jj) * 16 + l16) * 32 + rq);
      if (p == 0 && u + 1 < NT) STG(nbuf, u + 1, 1);        // k1 of t+1
      if (p == STG2 && u + 2 < NT) STG(buf, u + 2, 0);      // k0 of t+2
      __builtin_amdgcn_sched_barrier(0);
      __builtin_amdgcn_s_barrier();
      asm volatile("s_waitcnt lgkmcnt(0)" ::: "memory");
      __builtin_amdgcn_sched_barrier(0);
      __builtin_amdgcn_s_setprio(1);
#pragma unroll
      for (int jj = 0; jj < NF; jj++)
#pragma unroll
        for (int i = 0; i < M_REP; i++)
          acc[i][j0 + jj] = __builtin_amdgcn_mfma_f32_16x16x32_bf16(
              af[i], bfv[jj], acc[i][j0 + jj], 0, 0, 0);
      __builtin_amdgcn_s_setprio(0);
      if (p == NPH - 1 && u + 1 < NT) {  // tile-end counted wait
        __builtin_amdgcn_sched_barrier(0);
        if (u + 2 < NT) {
          if (BM == 256) asm volatile("s_waitcnt vmcnt(4)" ::: "memory");
          else           asm volatile("s_waitcnt vmcnt(3)" ::: "memory");
        } else {
          asm volatile("s_waitcnt vmcnt(0)" ::: "memory");
        }
      }
      __builtin_amdgcn_sched_barrier(0);
      __builtin_amdgcn_s_barrier();
      __builtin_amdgcn_sched_barrier(0);
    }
  }
#undef STG
#pragma unroll
  for (int i = 0; i < M_REP; i++)
#pragma unroll
    for (int jj = 0; jj < 4; jj++)
#pragma unroll
      for (int r = 0; r < 4; r++) {
        const int m = bm + wm + i * 16 + quad * 4 + r;
        const int n = bn + wn + jj * 16 + l16;
        const size_t idx = (size_t)m * N + n;
        const float v = acc[i][jj][r];
        if (MODE == 1) {
          outf[idx] = v + res[idx];
        } else if (MODE == 2) {
          const float z = v + bias[n];
          const float u = z * (0.7978845608f + 0.03567740814f * z * z);
          const float e = fminf(u * 2.885390082f, 80.f);
          const float tt = exp2fast(e);
          outb[idx] = f2b(z * tt * rcpfast(tt + 1.0f));
        } else if (MODE == 3) {
          outf[idx] = v + bias[n] + res[idx];
        } else {  // MODE 4
          outb[idx] = f2b(v);
        }
      }
}

// ---------------- GEMM C (NEW): barrier-free per-wave-private pipeline -----
// 128x128 tile, 4 waves (2Mx2N); each wave owns a private 16KB dbuf LDS
// slice holding ITS 64 A-rows + 64 B-rows per 32-k tile. No cross-wave LDS
// sharing => ZERO s_barrier in the K-loop. Per iter: ds_read own buf ->
// lgkm(0) (buf free) -> STG tile tt+2 into it -> MFMA -> counted vmcnt(8)
// on own loads. Waves drift freely (vmcnt is per-wave); a straggling load
// stalls one wave, not the CU. LDS 64KB -> 2 blocks/CU (8 waves).
// LDS micro-layout/swizzle pair = round-0 proven (zero conflicts).
template <int MODE, int NBN>
__global__ __launch_bounds__(256, 2) void gemm_pw(
    const unsigned short* __restrict__ A, const unsigned short* __restrict__ B,
    int M, int N, int K, float* __restrict__ outf, unsigned short* __restrict__ outb,
    const float* __restrict__ res, const float* __restrict__ bias) {
  __shared__ __align__(16) unsigned short L[4 * 8192];  // 4 waves x 16KB
  const int bid = blockIdx.x;
  const int j8 = bid & 7, g = bid >> 3;
  const int bm = ((g / NBN) * 8 + j8) * 128;
  const int bn = (g % NBN) * 128;
  const int t = threadIdx.x, wave = t >> 6, lane = t & 63;
  const int quad = lane >> 4, l16 = lane & 15;
  const int wm = (wave >> 1) * 64, wn = (wave & 1) * 64;
  const int r16 = lane >> 2;
  const int cs8 = (((lane & 3) ^ ((lane >> 3) & 3)) * 8);
  const unsigned short* Ag[4];
  const unsigned short* Bg[4];
#pragma unroll
  for (int i = 0; i < 4; i++) {
    Ag[i] = A + (size_t)(bm + wm + i * 16 + r16) * K + cs8;
    Bg[i] = B + (size_t)(bn + wn + i * 16 + r16) * K + cs8;
  }
  unsigned short* Wb = L + wave * 8192;  // [buf:2][{A,B}:2][2048 shorts]
#define STG(tt, bi)                                                          \
  do {                                                                       \
    const size_t ko_ = (size_t)(tt) * 32;                                    \
    _Pragma("unroll") for (int i_ = 0; i_ < 4; i_++) {                       \
      async_ld16(Ag[i_] + ko_, Wb + (bi) * 4096 + i_ * 512);                 \
      async_ld16(Bg[i_] + ko_, Wb + (bi) * 4096 + 2048 + i_ * 512);          \
    }                                                                        \
  } while (0)
  f32x4 acc[4][4] = {};
  const int NT = K >> 5;
  const int swg = (l16 >> 1) & 3;  // read-side swizzle key
  // prologue: tiles 0,1 in flight (16 loads); counted wait for tile 0 only.
  STG(0, 0);
  STG(1, 1);
  asm volatile("s_waitcnt vmcnt(8)" ::: "memory");
  __builtin_amdgcn_sched_barrier(0);
  for (int tt = 0; tt < NT; ++tt) {
    const int cur = tt & 1;
    const unsigned short* Ab = Wb + cur * 4096;
    const unsigned short* Bb = Ab + 2048;
    bf16x8 af[4], bfv[4];
#pragma unroll
    for (int i = 0; i < 4; i++)
      af[i] = *(const bf16x8*)(Ab + (i * 16 + l16) * 32 + (quad ^ swg) * 8);
#pragma unroll
    for (int j = 0; j < 4; j++)
      bfv[j] = *(const bf16x8*)(Bb + (j * 16 + l16) * 32 + (quad ^ swg) * 8);
    // own reads landed -> buf[cur] free for tile tt+2
    asm volatile("s_waitcnt lgkmcnt(0)" ::: "memory");
    __builtin_amdgcn_sched_barrier(0);
    if (tt + 2 < NT) STG(tt + 2, cur);
    __builtin_amdgcn_sched_barrier(0);
    __builtin_amdgcn_s_setprio(1);
#pragma unroll
    for (int j = 0; j < 4; j++)
#pragma unroll
      for (int i = 0; i < 4; i++)
        acc[i][j] = __builtin_amdgcn_mfma_f32_16x16x32_bf16(af[i], bfv[j],
                                                            acc[i][j], 0, 0, 0);
    __builtin_amdgcn_s_setprio(0);
    if (tt + 1 < NT) {
      __builtin_amdgcn_sched_barrier(0);
      // counted: tile tt+1 (own 8 oldest loads) resident; tt+2 in flight.
      if (tt + 2 < NT) asm volatile("s_waitcnt vmcnt(8)" ::: "memory");
      else             asm volatile("s_waitcnt vmcnt(0)" ::: "memory");
      __builtin_amdgcn_sched_barrier(0);
    }
  }
#undef STG
#pragma unroll
  for (int i = 0; i < 4; i++)
#pragma unroll
    for (int jj = 0; jj < 4; jj++)
#pragma unroll
      for (int r = 0; r < 4; r++) {
        const int m = bm + wm + i * 16 + quad * 4 + r;
        const int n = bn + wn + jj * 16 + l16;
        const size_t idx = (size_t)m * N + n;
        const float v = acc[i][jj][r];
        if (MODE == 1) {
          outf[idx] = v + res[idx];
        } else if (MODE == 2) {
          const float z = v + bias[n];
          const float u = z * (0.7978845608f + 0.03567740814f * z * z);
          const float e = fminf(u * 2.885390082f, 80.f);
          const float tt2 = exp2fast(e);
          outb[idx] = f2b(z * tt2 * rcpfast(tt2 + 1.0f));
        } else if (MODE == 3) {
          outf[idx] = v + bias[n] + res[idx];
        } else {  // MODE 4
          outb[idx] = f2b(v);
        }
      }
}

// ---------------- fused RoPE + V-transpose ---------------------------------
__device__ __forceinline__ u32 rope2(u32 in, float c, float sn, float sc) {
  const float a = b2f((unsigned short)(in & 0xffff));
  const float b = b2f((unsigned short)(in >> 16));
  return (u32)f2b((a * c - b * sn) * sc) | ((u32)f2b((a * sn + b * c) * sc) << 16);
}
__global__ __launch_bounds__(256) void ropevt_kernel(const unsigned short* __restrict__ qkv,
                                                     const float* __restrict__ cb,
                                                     const float* __restrict__ sb,
                                                     unsigned short* __restrict__ qh,
                                                     unsigned short* __restrict__ kh,
                                                     unsigned short* __restrict__ vt) {
  __shared__ unsigned short tile[64][72];
  const int blk = blockIdx.x;
  if (blk < 4096) {
    const int tid = blk * 256 + threadIdx.x;  // S*NH*8 threads
    const int ii = tid & 7, head = (tid >> 3) & 15, s = tid >> 7;
    const float4 cv = *(const float4*)(cb + s * 32 + ii * 4);
    const float4 sv = *(const float4*)(sb + s * 32 + ii * 4);
    const unsigned short* base = qkv + (size_t)s * 3072 + head * 64 + ii * 8;
    const uint4 qa = *(const uint4*)base;
    const uint4 ka = *(const uint4*)(base + 1024);
    const int seg = s >> 10, l = s & 1023;
    const size_t o = ((size_t)((seg * 16 + head) * 1024 + l)) * 64 + ii * 8;
    const float QSC = 0.125f * 1.44269504f;
    uint4 qo, ko;
    qo.x = rope2(qa.x, cv.x, sv.x, QSC); ko.x = rope2(ka.x, cv.x, sv.x, 1.f);
    qo.y = rope2(qa.y, cv.y, sv.y, QSC); ko.y = rope2(ka.y, cv.y, sv.y, 1.f);
    qo.z = rope2(qa.z, cv.z, sv.z, QSC); ko.z = rope2(ka.z, cv.z, sv.z, 1.f);
    qo.w = rope2(qa.w, cv.w, sv.w, QSC); ko.w = rope2(ka.w, cv.w, sv.w, 1.f);
    *(uint4*)(qh + o) = qo;
    *(uint4*)(kh + o) = ko;
    return;
  }
  const int b = blk - 4096;  // 8*16*16
  const int lt = b & 15, head = (b >> 4) & 15, seg = b >> 8;
  const int t = threadIdx.x;
  const int r = t >> 2, c0 = (t & 3) * 16;
  const unsigned short* src =
      qkv + ((size_t)(seg * 1024 + lt * 64 + r)) * 3072 + 2048 + head * 64 + c0;
#pragma unroll
  for (int k = 0; k < 16; k++) tile[r][c0 + k] = src[k];
  __syncthreads();
  unsigned short* dst =
      vt + ((size_t)((seg * 16 + head) * 64 + r)) * 1024 + lt * 64 + c0;
#pragma unroll
  for (int k = 0; k < 16; k++) dst[k] = tile[c0 + k][r];
}

// ---------------- flash attention, 32x32x16 MFMA, in-register P ------------
__global__ __launch_bounds__(256) void attn_kernel(const unsigned short* __restrict__ qh,
                                                   const unsigned short* __restrict__ kh,
                                                   const unsigned short* __restrict__ vt,
                                                   unsigned short* __restrict__ out) {
  __shared__ __align__(16) unsigned short Qs[128 * 64];
  __shared__ __align__(16) unsigned short Ks[64 * 64];
  __shared__ __align__(16) unsigned short Vs[64 * 64];  // [hd][key]
  __shared__ float wl[128];
  const int b = blockIdx.x;
  const int head = b & 15, seg = (b >> 4) & 7, qt = b >> 7;
  const int t = threadIdx.x, wave = t >> 6, lane = t & 63;
  const int h = lane >> 5, q31 = lane & 31;
  const size_t sh = (size_t)(seg * 16 + head);
  const unsigned short* qbase = qh + (sh * 1024 + (size_t)qt * 128) * 64;
  const unsigned short* kbase = kh + sh * 1024 * 64;
  const unsigned short* vbase = vt + sh * 64 * 1024;
  const int r8 = lane >> 3;
  const int c8 = ((lane & 7) ^ (r8 & 7)) * 8;  // swizzled source col (shorts)
#pragma unroll
  for (int cc = 0; cc < 4; cc++) {  // stage Q once (16KB, 16 chunks)
    const int chunk = wave * 4 + cc;
    async_ld16(qbase + (size_t)(chunk * 8 + r8) * 64 + c8, Qs + chunk * 512);
  }
  const int qrow_l = wave * 32 + q31;          // this lane's query row in tile
  const int qsw = qrow_l & 7;                  // Qs swizzle key
  bf16x8 qf[4];                                // Q B-frags, loaded once
  float lsum = 0.f;
  f32x16 oacc[2] = {};

  for (int kt = 0; kt < 16; kt++) {
    const int ch0 = wave * 2;
    async_ld16(kbase + (size_t)(kt * 64 + ch0 * 8 + r8) * 64 + c8, Ks + ch0 * 512);
    async_ld16(kbase + (size_t)(kt * 64 + ch0 * 8 + 8 + r8) * 64 + c8, Ks + ch0 * 512 + 512);
    async_ld16(vbase + (size_t)(ch0 * 8 + r8) * 1024 + kt * 64 + c8, Vs + ch0 * 512);
    async_ld16(vbase + (size_t)(ch0 * 8 + 8 + r8) * 1024 + kt * 64 + c8, Vs + ch0 * 512 + 512);
    __syncthreads();
    if (kt == 0) {
#pragma unroll
      for (int ks = 0; ks < 4; ks++)
        qf[ks] = *(const bf16x8*)(Qs + qrow_l * 64 + (((2 * ks + h) ^ qsw)) * 8);
    }
    // S^T = K.Q^T : 2 key tiles x 4 ksteps
    f32x16 st[2] = {{}, {}};
#pragma unroll
    for (int T = 0; T < 2; T++) {
      const int krow = 32 * T + q31;
      const int ksw = krow & 7;
#pragma unroll
      for (int ks = 0; ks < 4; ks++) {
        const bf16x8 kf = *(const bf16x8*)(Ks + krow * 64 + (((2 * ks + h) ^ ksw)) * 8);
        st[T] = __builtin_amdgcn_mfma_f32_32x32x16_bf16(kf, qf[ks], st[T], 0, 0, 0);
      }
    }
    // p = exp2(s) (q pre-scaled by log2e/8); pack bf16 pairs per group
    u32 pk[2][4][2];
#pragma unroll
    for (int T = 0; T < 2; T++)
#pragma unroll
      for (int g = 0; g < 4; g++)
#pragma unroll
        for (int e = 0; e < 2; e++) {
          const float plo = exp2fast(st[T][4 * g + 2 * e]);
          const float phi = exp2fast(st[T][4 * g + 2 * e + 1]);
          lsum += plo + phi;
          pk[T][g][e] = (u32)f2b(plo) | ((u32)f2b(phi) << 16);
        }
    // half-wave exchange of the cross quads
    u32 rcv[2][4];
#pragma unroll
    for (int T = 0; T < 2; T++) {
      const u32 p0 = h ? pk[T][0][0] : pk[T][1][0];
      const u32 p1 = h ? pk[T][0][1] : pk[T][1][1];
      const u32 p2 = h ? pk[T][2][0] : pk[T][3][0];
      const u32 p3 = h ? pk[T][2][1] : pk[T][3][1];
      rcv[T][0] = (u32)__shfl_xor((int)p0, 32, 64);
      rcv[T][1] = (u32)__shfl_xor((int)p1, 32, 64);
      rcv[T][2] = (u32)__shfl_xor((int)p2, 32, 64);
      rcv[T][3] = (u32)__shfl_xor((int)p3, 32, 64);
    }
    // O += P.V
#pragma unroll
    for (int tt = 0; tt < 4; tt++) {
      const int T = tt >> 1, uu = tt & 1;
      union { u32 u[4]; bf16x8 v; } af;
      if (h == 0) {
        af.u[0] = pk[T][2 * uu][0];
        af.u[1] = pk[T][2 * uu][1];
        af.u[2] = rcv[T][2 * uu];
        af.u[3] = rcv[T][2 * uu + 1];
      } else {
        af.u[0] = rcv[T][2 * uu];
        af.u[1] = rcv[T][2 * uu + 1];
        af.u[2] = pk[T][2 * uu + 1][0];
        af.u[3] = pk[T][2 * uu + 1][1];
      }
#pragma unroll
      for (int ot = 0; ot < 2; ot++) {
        const int vrow = 32 * ot + q31;
        const int vsw = vrow & 7;
        const bf16x8 bv = *(const bf16x8*)(Vs + vrow * 64 + (((2 * tt + h) ^ vsw)) * 8);
        oacc[ot] = __builtin_amdgcn_mfma_f32_32x32x16_bf16(af.v, bv, oacc[ot], 0, 0, 0);
      }
    }
    __syncthreads();
  }
  // epilogue: full row-sum, normalize, store
  lsum += __shfl_xor(lsum, 32, 64);
  if (h == 0) wl[wave * 32 + q31] = lsum;
  const int qglob = seg * 1024 + qt * 128 + wave * 32;
#pragma unroll
  for (int g = 0; g < 4; g++) {
    const float4 lv = *(const float4*)&wl[wave * 32 + 8 * g + 4 * h];
#pragma unroll
    for (int m = 0; m < 4; m++) {
      const int r16 = 4 * g + m;
      const int qrow = qglob + m + 8 * g + 4 * h;
      const float invl = rcpfast((&lv.x)[m]);
#pragma unroll
      for (int ot = 0; ot < 2; ot++)
        out[(size_t)qrow * 1024 + head * 64 + 32 * ot + q31] = f2b(oacc[ot][r16] * invl);
    }
  }
}

// ---------------------------------------------------------------------------
extern "C" void kernel_launch(void* const* d_in, const int* in_sizes, int n_in,
                              void* d_out, int out_size, void* d_ws, size_t ws_size,
                              hipStream_t stream) {
  (void)in_sizes; (void)n_in; (void)out_size; (void)ws_size;
  const float* x    = (const float*)d_in[0];
  const float* wqkv = (const float*)d_in[1];
  const float* wo   = (const float*)d_in[2];
  const float* ln0g = (const float*)d_in[3];
  const float* ln0b = (const float*)d_in[4];
  const float* ln1g = (const float*)d_in[5];
  const float* ln1b = (const float*)d_in[6];
  const float* fc0w = (const float*)d_in[7];
  const float* fc0b = (const float*)d_in[8];
  const float* fc1w = (const float*)d_in[9];
  const float* fc1b = (const float*)d_in[10];
  const float* rc   = (const float*)d_in[11];
  const float* rsn  = (const float*)d_in[12];
  float* out = (float*)d_out;
  char* w = (char*)d_ws;
  const size_t MB = 1u << 20;
  unsigned short* hb    = (unsigned short*)(w + 0);
  unsigned short* bqkv  = (unsigned short*)(w + 16 * MB);
  unsigned short* bwo   = (unsigned short*)(w + 22 * MB);
  unsigned short* bfc0  = (unsigned short*)(w + 24 * MB);
  unsigned short* bfc1  = (unsigned short*)(w + 32 * MB);
  unsigned short* qhb   = (unsigned short*)(w + 40 * MB);
  unsigned short* khb   = (unsigned short*)(w + 56 * MB);
  unsigned short* vtb   = (unsigned short*)(w + 72 * MB);
  unsigned short* attnb = (unsigned short*)(w + 88 * MB);
  unsigned short* qkvb  = (unsigned short*)(w + 104 * MB);
  unsigned short* midb  = (unsigned short*)(w + 104 * MB);  // alias, qkvb dead

  // 1: weight casts + LN0 (one dispatch)
  castln_kernel<<<20480, 256, 0, stream>>>(wqkv, wo, fc0w, fc1w, bqkv,
                                           x, ln0g, ln0b, hb);
  // 2: QKV = hb @ wqkv^T   (p8, 256x256, 384 blk = 1.5/CU)
  gemm_p8<4, 12, 256><<<384, 512, 0, stream>>>(hb, bqkv, 8192, 3072, 1024,
                                               nullptr, qkvb, nullptr, nullptr);
  // 3: RoPE + V-transpose (one dispatch)
  ropevt_kernel<<<6144, 256, 0, stream>>>(qkvb, rc, rsn, qhb, khb, vtb);
  // 4: attention
  attn_kernel<<<1024, 256, 0, stream>>>(qhb, khb, vtb, attnb);
  // 5: WO: out = attn @ wo^T + x   (p8, 128x256, 256 blk = 1.0/CU)
  gemm_p8<1, 4, 128><<<256, 512, 0, stream>>>(attnb, bwo, 8192, 1024, 1024,
                                              out, nullptr, x, nullptr);
  // 6: LN1
  ln_kernel<<<8192, 256, 0, stream>>>(out, ln1g, ln1b, hb);
  // 7: FC0 (+bias, GELU) -> midb   (pw EXPERIMENT, 128^2, grid 2048)
  gemm_pw<2, 32><<<2048, 256, 0, stream>>>(hb, bfc0, 8192, 4096, 1024,
                                           nullptr, midb, nullptr, fc0b);
  // 8: FC1: out = mid @ fc1^T + bias + out   (p8, 128x256, 256 blk, K=4096)
  gemm_p8<3, 4, 128><<<256, 512, 0, stream>>>(midb, bfc1, 8192, 1024, 4096,
                                              out, nullptr, out, fc1b);
}

// Round 11
// 490.276 us; speedup vs baseline: 1.1287x; 1.1234x over previous
//
#include <hip/hip_runtime.h>
#include <math.h>

// ---------------------------------------------------------------------------
// VideoChat3 vision encoder block, bf16-MFMA pipeline. Round 18:
//  - r10 post-mortem: barrier-free pw falsified (FETCH 74->258MB: per-wave
//    duplicate staging misses L2; convoy wasn't the limit). FC0-bt8's FETCH
//    is already at the per-XCD compulsory floor (74MB ~ 16+8x8). FC0's 608
//    TF = the catalog's 2-phase ceiling (m233 607 / m230 682); 8-phase only
//    pays at deep K (our FC1-K4096-p8 747 TF vs FC0-K1024-p8 563 TF).
//    GEMM schedule space is exhausted at these shapes.
//  - This round: r8 pipeline exact (FC0 on bt8, banked 490.7us) + the ONE
//    unprofiled big consumer fixed: attn gets the r12-proven K/V double
//    buffer (stage kt+1 at top of iter kt; vmcnt(0)+raw barrier after the
//    MFMA+softmax work -> latency hidden) + Q-frags direct from global
//    (drops Qs LDS + its staging; 48.5 -> 32.5KB, 4 blocks/CU).
// S=8192, H=1024, NH=16, HD=64, NSEG=8, L=1024, MLP=4096.
// ---------------------------------------------------------------------------

typedef __bf16 bf16x8 __attribute__((ext_vector_type(8)));
typedef float f32x4 __attribute__((ext_vector_type(4)));
typedef float f32x16 __attribute__((ext_vector_type(16)));
typedef unsigned int u32;

__device__ __forceinline__ unsigned short f2b(float f) {  // RNE f32->bf16
  unsigned u = __float_as_uint(f);
  return (unsigned short)((u + 0x7FFFu + ((u >> 16) & 1u)) >> 16);
}
__device__ __forceinline__ float b2f(unsigned short h) {
  return __uint_as_float(((unsigned)h) << 16);
}
__device__ __forceinline__ void async_ld16(const void* g, void* l) {
  __builtin_amdgcn_global_load_lds((__attribute__((address_space(1))) void*)g,
                                   (__attribute__((address_space(3))) void*)l,
                                   16, 0, 0);
}
__device__ __forceinline__ float exp2fast(float x) {
#if __has_builtin(__builtin_amdgcn_exp2f)
  return __builtin_amdgcn_exp2f(x);
#else
  return exp2f(x);
#endif
}
__device__ __forceinline__ float rcpfast(float x) {
#if __has_builtin(__builtin_amdgcn_rcpf)
  return __builtin_amdgcn_rcpf(x);
#else
  return 1.0f / x;
#endif
}

// ---------------- fused: weight cast fp32->bf16  +  LN0 --------------------
__global__ __launch_bounds__(256) void castln_kernel(
    const float* __restrict__ w0, const float* __restrict__ w1,
    const float* __restrict__ w2, const float* __restrict__ w3,
    unsigned short* __restrict__ wdst,
    const float* __restrict__ x, const float* __restrict__ g,
    const float* __restrict__ bt, unsigned short* __restrict__ hout) {
  __shared__ float red[8];
  const int blk = blockIdx.x;
  if (blk < 12288) {
    const int t = blk * 256 + threadIdx.x;  // float4 groups
    const float* src;
    int off;
    if (t < 786432) { src = w0; off = t; }
    else if (t < 1048576) { src = w1; off = t - 786432; }
    else if (t < 2097152) { src = w2; off = t - 1048576; }
    else { src = w3; off = t - 2097152; }
    const float4 v = ((const float4*)src)[off];
    ushort4 o;
    o.x = f2b(v.x); o.y = f2b(v.y); o.z = f2b(v.z); o.w = f2b(v.w);
    ((ushort4*)wdst)[t] = o;
    return;
  }
  const int row = blk - 12288, t = threadIdx.x;
  const float4 v = ((const float4*)(x + (size_t)row * 1024))[t];
  float s = v.x + v.y + v.z + v.w;
  float s2 = v.x * v.x + v.y * v.y + v.z * v.z + v.w * v.w;
#pragma unroll
  for (int m = 1; m < 64; m <<= 1) {
    s += __shfl_xor(s, m, 64);
    s2 += __shfl_xor(s2, m, 64);
  }
  if ((t & 63) == 0) { red[t >> 6] = s; red[4 + (t >> 6)] = s2; }
  __syncthreads();
  const float ts = red[0] + red[1] + red[2] + red[3];
  const float ts2 = red[4] + red[5] + red[6] + red[7];
  const float mean = ts * (1.f / 1024.f);
  const float var = ts2 * (1.f / 1024.f) - mean * mean;
  const float inv = rsqrtf(var + 1e-5f);
  const float4 gv = ((const float4*)g)[t];
  const float4 bv = ((const float4*)bt)[t];
  ushort4 o;
  o.x = f2b((v.x - mean) * inv * gv.x + bv.x);
  o.y = f2b((v.y - mean) * inv * gv.y + bv.y);
  o.z = f2b((v.z - mean) * inv * gv.z + bv.z);
  o.w = f2b((v.w - mean) * inv * gv.w + bv.w);
  ((ushort4*)hout)[(size_t)row * 256 + t] = o;
}

// ---------------- layernorm (row of 1024) -> bf16 (standalone, LN1) --------
__global__ __launch_bounds__(256) void ln_kernel(const float* __restrict__ x,
                                                 const float* __restrict__ g,
                                                 const float* __restrict__ bt,
                                                 unsigned short* __restrict__ out) {
  __shared__ float red[8];
  const int row = blockIdx.x, t = threadIdx.x;
  const float4 v = ((const float4*)(x + (size_t)row * 1024))[t];
  float s = v.x + v.y + v.z + v.w;
  float s2 = v.x * v.x + v.y * v.y + v.z * v.z + v.w * v.w;
#pragma unroll
  for (int m = 1; m < 64; m <<= 1) {
    s += __shfl_xor(s, m, 64);
    s2 += __shfl_xor(s2, m, 64);
  }
  if ((t & 63) == 0) { red[t >> 6] = s; red[4 + (t >> 6)] = s2; }
  __syncthreads();
  const float ts = red[0] + red[1] + red[2] + red[3];
  const float ts2 = red[4] + red[5] + red[6] + red[7];
  const float mean = ts * (1.f / 1024.f);
  const float var = ts2 * (1.f / 1024.f) - mean * mean;
  const float inv = rsqrtf(var + 1e-5f);
  const float4 gv = ((const float4*)g)[t];
  const float4 bv = ((const float4*)bt)[t];
  ushort4 o;
  o.x = f2b((v.x - mean) * inv * gv.x + bv.x);
  o.y = f2b((v.y - mean) * inv * gv.y + bv.y);
  o.z = f2b((v.z - mean) * inv * gv.z + bv.z);
  o.w = f2b((v.w - mean) * inv * gv.w + bv.w);
  ((ushort4*)out)[(size_t)row * 256 + t] = o;
}

// ---------------- GEMM A (r3): BM x 256, 8-phase, 2x 32-k LDS slots --------
// MODE 1: outf = acc + res           MODE 2: outb = bf16(gelu(acc+bias))
// MODE 3: outf = acc + bias + res    MODE 4: outb = bf16(acc)
template <int MODE, int NBN, int BM>
__global__ __launch_bounds__(512, 2) void gemm_p8(
    const unsigned short* __restrict__ A, const unsigned short* __restrict__ B,
    int M, int N, int K, float* __restrict__ outf, unsigned short* __restrict__ outb,
    const float* __restrict__ res, const float* __restrict__ bias) {
  constexpr int NPH = (BM == 256) ? 4 : 2;   // phases per K-tile
  constexpr int NF = (BM == 256) ? 2 : 4;    // B frags per phase
  constexpr int M_REP = BM / 32;             // 8 | 4 (per-wave M frags)
  constexpr int AI = BM / 128;               // A stage insts per slot per wave
  constexpr int STG2 = (BM == 256) ? 2 : 1;  // phase staging k0[t+2]
  __shared__ __align__(16) unsigned short As[2][2][BM * 32];
  __shared__ __align__(16) unsigned short Bs[2][2][256 * 32];
  const int bid = blockIdx.x;
  const int j8 = bid & 7, g = bid >> 3;
  const int bm = ((g / NBN) * 8 + j8) * BM;
  const int bn = (g % NBN) * 256;
  const int t = threadIdx.x, wave = t >> 6, lane = t & 63;
  const int quad = lane >> 4, l16 = lane & 15;
  const int wm = (wave >> 2) * (M_REP * 16);
  const int wn = (wave & 3) * 64;
  const int r16 = lane >> 2;
  const int cs8 = (((lane & 3) ^ ((lane >> 3) & 3)) * 8);
  const unsigned short* AgS[AI];
  unsigned short* AlS[AI];
#pragma unroll
  for (int i = 0; i < AI; i++) {
    const int r0 = wave * (AI * 16) + i * 16;
    AgS[i] = A + (size_t)(bm + r0 + r16) * K + cs8;
    AlS[i] = &As[0][0][r0 * 32];
  }
  const unsigned short* BgS[2];
  unsigned short* BlS[2];
#pragma unroll
  for (int i = 0; i < 2; i++) {
    const int r0 = wave * 32 + i * 16;
    BgS[i] = B + (size_t)(bn + r0 + r16) * K + cs8;
    BlS[i] = &Bs[0][0][r0 * 32];
  }
#define STG(bi, kt, ks)                                                      \
  do {                                                                       \
    _Pragma("unroll") for (int i_ = 0; i_ < AI; i_++)                        \
        async_ld16(AgS[i_] + (size_t)(kt) * 64 + (ks) * 32,                  \
                   AlS[i_] + ((bi) * 2 + (ks)) * (BM * 32));                 \
    _Pragma("unroll") for (int i_ = 0; i_ < 2; i_++)                         \
        async_ld16(BgS[i_] + (size_t)(kt) * 64 + (ks) * 32,                  \
                   BlS[i_] + ((bi) * 2 + (ks)) * (256 * 32));                \
  } while (0)

  f32x4 acc[M_REP][4] = {};
  const int NT = K >> 6;
  const int rq = ((quad ^ ((l16 >> 1) & 3)) * 8);  // read-side swizzled chunk
  STG(0, 0, 0);
  STG(0, 0, 1);
  STG(1, 1, 0);
  __builtin_amdgcn_sched_barrier(0);
  if (BM == 256) asm volatile("s_waitcnt vmcnt(4)" ::: "memory");
  else           asm volatile("s_waitcnt vmcnt(3)" ::: "memory");
  __builtin_amdgcn_sched_barrier(0);
  __builtin_amdgcn_s_barrier();
  __builtin_amdgcn_sched_barrier(0);

  bf16x8 af[M_REP];
  for (int u = 0; u < NT; ++u) {
    const int buf = u & 1, nbuf = buf ^ 1;
#pragma unroll
    for (int p = 0; p < NPH; ++p) {
      const int ks = (NPH == 4) ? (p >> 1) : p;
      const int j0 = (NPH == 4) ? (p & 1) * 2 : 0;
      const unsigned short* Ab = &As[buf][ks][0];
      const unsigned short* Bb = &Bs[buf][ks][0];
      if (NPH == 2 || (p & 1) == 0) {
#pragma unroll
        for (int i = 0; i < M_REP; i++)
          af[i] = *(const bf16x8*)(Ab + (wm + i * 16 + l16) * 32 + rq);
      }
      bf16x8 bfv[NF];
#pragma unroll
      for (int jj = 0; jj < NF; jj++)
        bfv[jj] = *(const bf16x8*)(Bb + (wn + (j0 + jj) * 16 + l16) * 32 + rq);
      if (p == 0 && u + 1 < NT) STG(nbuf, u + 1, 1);        // k1 of t+1
      if (p == STG2 && u + 2 < NT) STG(buf, u + 2, 0);      // k0 of t+2
      __builtin_amdgcn_sched_barrier(0);
      __builtin_amdgcn_s_barrier();
      asm volatile("s_waitcnt lgkmcnt(0)" ::: "memory");
      __builtin_amdgcn_sched_barrier(0);
      __builtin_amdgcn_s_setprio(1);
#pragma unroll
      for (int jj = 0; jj < NF; jj++)
#pragma unroll
        for (int i = 0; i < M_REP; i++)
          acc[i][j0 + jj] = __builtin_amdgcn_mfma_f32_16x16x32_bf16(
              af[i], bfv[jj], acc[i][j0 + jj], 0, 0, 0);
      __builtin_amdgcn_s_setprio(0);
      if (p == NPH - 1 && u + 1 < NT) {  // tile-end counted wait
        __builtin_amdgcn_sched_barrier(0);
        if (u + 2 < NT) {
          if (BM == 256) asm volatile("s_waitcnt vmcnt(4)" ::: "memory");
          else           asm volatile("s_waitcnt vmcnt(3)" ::: "memory");
        } else {
          asm volatile("s_waitcnt vmcnt(0)" ::: "memory");
        }
      }
      __builtin_amdgcn_sched_barrier(0);
      __builtin_amdgcn_s_barrier();
      __builtin_amdgcn_sched_barrier(0);
    }
  }
#undef STG
#pragma unroll
  for (int i = 0; i < M_REP; i++)
#pragma unroll
    for (int jj = 0; jj < 4; jj++)
#pragma unroll
      for (int r = 0; r < 4; r++) {
        const int m = bm + wm + i * 16 + quad * 4 + r;
        const int n = bn + wn + jj * 16 + l16;
        const size_t idx = (size_t)m * N + n;
        const float v = acc[i][jj][r];
        if (MODE == 1) {
          outf[idx] = v + res[idx];
        } else if (MODE == 2) {
          const float z = v + bias[n];
          const float u = z * (0.7978845608f + 0.03567740814f * z * z);
          const float e = fminf(u * 2.885390082f, 80.f);
          const float tt = exp2fast(e);
          outb[idx] = f2b(z * tt * rcpfast(tt + 1.0f));
        } else if (MODE == 3) {
          outf[idx] = v + bias[n] + res[idx];
        } else {  // MODE 4
          outb[idx] = f2b(v);
        }
      }
}

// ---------------- GEMM B (r2): 256xBN, BK=64, 2-phase counted pipeline -----
template <int MODE, int NBN, int BN>
__global__ __launch_bounds__(512, 2) void gemm_bt8(
    const unsigned short* __restrict__ A, const unsigned short* __restrict__ B,
    int M, int N, int K, float* __restrict__ outf, unsigned short* __restrict__ outb,
    const float* __restrict__ res, const float* __restrict__ bias) {
  constexpr int NBI = BN / 64;             // B staging insts per wave (2|4)
  constexpr int WN_WAVES = BN / 64;        // waves tiling N (2|4)
  constexpr int WM_WAVES = 8 / WN_WAVES;   // waves tiling M (4|2)
  constexpr int M_REP = (256 / WM_WAVES) / 16;  // 4|8
  constexpr int N_REP = 4;
  __shared__ __align__(16) unsigned short As[2][256 * 64];
  __shared__ __align__(16) unsigned short Bs[2][BN * 64];
  const int bid = blockIdx.x;
  const int j8 = bid & 7, g = bid >> 3;
  const int bm = ((g / NBN) * 8 + j8) * 256;
  const int bn = (g % NBN) * BN;
  const int t = threadIdx.x, wave = t >> 6, lane = t & 63;
  const int quad = lane >> 4, l16 = lane & 15;
  const int wm = (wave / WN_WAVES) * (M_REP * 16);
  const int wn = (wave % WN_WAVES) * 64;
  const int l8 = lane >> 3;
  const int cs = ((lane & 7) ^ (l8 & 7)) * 8;
  const unsigned short* Ag[4];
  unsigned short* Al[4];
#pragma unroll
  for (int i = 0; i < 4; i++) {
    const int r = wave * 32 + i * 8;
    Ag[i] = A + (size_t)(bm + r + l8) * K + cs;
    Al[i] = &As[0][r * 64];
  }
  const unsigned short* Bg[NBI];
  unsigned short* Bl[NBI];
#pragma unroll
  for (int i = 0; i < NBI; i++) {
    const int r = wave * (NBI * 8) + i * 8;
    Bg[i] = B + (size_t)(bn + r + l8) * K + cs;
    Bl[i] = &Bs[0][r * 64];
  }
#define STAGE(bi, k0)                                                        \
  do {                                                                       \
    _Pragma("unroll") for (int i_ = 0; i_ < 4; i_++)                         \
        async_ld16(Ag[i_] + (k0), Al[i_] + (bi) * (256 * 64));               \
    _Pragma("unroll") for (int i_ = 0; i_ < NBI; i_++)                       \
        async_ld16(Bg[i_] + (k0), Bl[i_] + (bi) * (BN * 64));                \
  } while (0)

  f32x4 acc[M_REP][N_REP] = {};
  const int NT = K >> 6;
  const int swk = l16 & 7;  // ds_read swizzle key (= row&7 for frag rows)
  STAGE(0, 0);
  STAGE(1, 64);
  if (BN == 256) asm volatile("s_waitcnt vmcnt(8)" ::: "memory");
  else           asm volatile("s_waitcnt vmcnt(6)" ::: "memory");
  __builtin_amdgcn_sched_barrier(0);
  __builtin_amdgcn_s_barrier();
  __builtin_amdgcn_sched_barrier(0);
  int k0 = 128;
  for (int tI = 0; tI < NT; ++tI) {
    const int cur = tI & 1;
    const unsigned short* Ab = &As[cur][0];
    const unsigned short* Bb = &Bs[cur][0];
#pragma unroll
    for (int ks = 0; ks < 2; ks++) {
      bf16x8 af[M_REP], bfv[N_REP];
#pragma unroll
      for (int i = 0; i < M_REP; i++)
        af[i] = *(const bf16x8*)(Ab + (wm + i * 16 + l16) * 64 +
                                 (((ks * 4 + quad) ^ swk) * 8));
#pragma unroll
      for (int j = 0; j < N_REP; j++)
        bfv[j] = *(const bf16x8*)(Bb + (wn + j * 16 + l16) * 64 +
                                  (((ks * 4 + quad) ^ swk) * 8));
      __builtin_amdgcn_s_setprio(1);
#pragma unroll
      for (int j = 0; j < N_REP; j++)
#pragma unroll
        for (int i = 0; i < M_REP; i++)
          acc[i][j] = __builtin_amdgcn_mfma_f32_16x16x32_bf16(af[i], bfv[j],
                                                              acc[i][j], 0, 0, 0);
      __builtin_amdgcn_s_setprio(0);
    }
    if (tI + 1 == NT) break;
    __builtin_amdgcn_sched_barrier(0);
    __builtin_amdgcn_s_barrier();  // all waves done reading buf[cur]
    __builtin_amdgcn_sched_barrier(0);
    if (tI + 2 < NT) {
      STAGE(cur, k0);              // overwrite buf[cur] with tile tI+2
      k0 += 64;
      if (BN == 256) asm volatile("s_waitcnt vmcnt(8)" ::: "memory");
      else           asm volatile("s_waitcnt vmcnt(6)" ::: "memory");
    } else {
      asm volatile("s_waitcnt vmcnt(0)" ::: "memory");
    }
    __builtin_amdgcn_sched_barrier(0);
    __builtin_amdgcn_s_barrier();  // all waves' next tile resident
    __builtin_amdgcn_sched_barrier(0);
  }
#undef STAGE
#pragma unroll
  for (int i = 0; i < M_REP; i++)
#pragma unroll
    for (int j = 0; j < N_REP; j++)
#pragma unroll
      for (int r = 0; r < 4; r++) {
        const int m = bm + wm + i * 16 + quad * 4 + r;
        const int n = bn + wn + j * 16 + l16;
        const size_t idx = (size_t)m * N + n;
        const float v = acc[i][j][r];
        if (MODE == 1) {
          outf[idx] = v + res[idx];
        } else if (MODE == 2) {
          const float z = v + bias[n];
          const float u = z * (0.7978845608f + 0.03567740814f * z * z);
          const float e = fminf(u * 2.885390082f, 80.f);
          const float tt = exp2fast(e);
          outb[idx] = f2b(z * tt * rcpfast(tt + 1.0f));
        } else if (MODE == 3) {
          outf[idx] = v + bias[n] + res[idx];
        } else {  // MODE 4
          outb[idx] = f2b(v);
        }
      }
}

// ---------------- fused RoPE + V-transpose ---------------------------------
__device__ __forceinline__ u32 rope2(u32 in, float c, float sn, float sc) {
  const float a = b2f((unsigned short)(in & 0xffff));
  const float b = b2f((unsigned short)(in >> 16));
  return (u32)f2b((a * c - b * sn) * sc) | ((u32)f2b((a * sn + b * c) * sc) << 16);
}
__global__ __launch_bounds__(256) void ropevt_kernel(const unsigned short* __restrict__ qkv,
                                                     const float* __restrict__ cb,
                                                     const float* __restrict__ sb,
                                                     unsigned short* __restrict__ qh,
                                                     unsigned short* __restrict__ kh,
                                                     unsigned short* __restrict__ vt) {
  __shared__ unsigned short tile[64][72];
  const int blk = blockIdx.x;
  if (blk < 4096) {
    const int tid = blk * 256 + threadIdx.x;  // S*NH*8 threads
    const int ii = tid & 7, head = (tid >> 3) & 15, s = tid >> 7;
    const float4 cv = *(const float4*)(cb + s * 32 + ii * 4);
    const float4 sv = *(const float4*)(sb + s * 32 + ii * 4);
    const unsigned short* base = qkv + (size_t)s * 3072 + head * 64 + ii * 8;
    const uint4 qa = *(const uint4*)base;
    const uint4 ka = *(const uint4*)(base + 1024);
    const int seg = s >> 10, l = s & 1023;
    const size_t o = ((size_t)((seg * 16 + head) * 1024 + l)) * 64 + ii * 8;
    const float QSC = 0.125f * 1.44269504f;
    uint4 qo, ko;
    qo.x = rope2(qa.x, cv.x, sv.x, QSC); ko.x = rope2(ka.x, cv.x, sv.x, 1.f);
    qo.y = rope2(qa.y, cv.y, sv.y, QSC); ko.y = rope2(ka.y, cv.y, sv.y, 1.f);
    qo.z = rope2(qa.z, cv.z, sv.z, QSC); ko.z = rope2(ka.z, cv.z, sv.z, 1.f);
    qo.w = rope2(qa.w, cv.w, sv.w, QSC); ko.w = rope2(ka.w, cv.w, sv.w, 1.f);
    *(uint4*)(qh + o) = qo;
    *(uint4*)(kh + o) = ko;
    return;
  }
  const int b = blk - 4096;  // 8*16*16
  const int lt = b & 15, head = (b >> 4) & 15, seg = b >> 8;
  const int t = threadIdx.x;
  const int r = t >> 2, c0 = (t & 3) * 16;
  const unsigned short* src =
      qkv + ((size_t)(seg * 1024 + lt * 64 + r)) * 3072 + 2048 + head * 64 + c0;
#pragma unroll
  for (int k = 0; k < 16; k++) tile[r][c0 + k] = src[k];
  __syncthreads();
  unsigned short* dst =
      vt + ((size_t)((seg * 16 + head) * 64 + r)) * 1024 + lt * 64 + c0;
#pragma unroll
  for (int k = 0; k < 16; k++) dst[k] = tile[c0 + k][r];
}

// ---------------- flash attention, 32x32x16 MFMA, in-register P ------------
// K/V double-buffered (stage kt+1 at top of iter kt; vmcnt(0) + raw barrier
// at the bottom, AFTER the MFMA+softmax work -> staging latency hidden).
// Q frags direct from global (each lane owns its q-row). LDS 32.5KB ->
// 4 blocks/CU co-resident (grid 1024 = 4.0/CU).
__global__ __launch_bounds__(256) void attn_kernel(const unsigned short* __restrict__ qh,
                                                   const unsigned short* __restrict__ kh,
                                                   const unsigned short* __restrict__ vt,
                                                   unsigned short* __restrict__ out) {
  __shared__ __align__(16) unsigned short Ks[2 * 4096];
  __shared__ __align__(16) unsigned short Vs[2 * 4096];  // [hd][key]
  __shared__ float wl[128];
  const int b = blockIdx.x;
  const int head = b & 15, seg = (b >> 4) & 7, qt = b >> 7;
  const int t = threadIdx.x, wave = t >> 6, lane = t & 63;
  const int h = lane >> 5, q31 = lane & 31;
  const size_t sh = (size_t)(seg * 16 + head);
  const unsigned short* qbase = qh + (sh * 1024 + (size_t)qt * 128) * 64;
  const unsigned short* kbase = kh + sh * 1024 * 64;
  const unsigned short* vbase = vt + sh * 64 * 1024;
  const int r8 = lane >> 3;
  const int c8 = ((lane & 7) ^ (r8 & 7)) * 8;  // swizzled source col (shorts)
  const int ch0 = wave * 2;
#define STAGEKV(kt, bi)                                                        \
  do {                                                                         \
    async_ld16(kbase + (size_t)((kt) * 64 + ch0 * 8 + r8) * 64 + c8,           \
               Ks + (bi) * 4096 + ch0 * 512);                                  \
    async_ld16(kbase + (size_t)((kt) * 64 + ch0 * 8 + 8 + r8) * 64 + c8,       \
               Ks + (bi) * 4096 + ch0 * 512 + 512);                            \
    async_ld16(vbase + (size_t)(ch0 * 8 + r8) * 1024 + (kt) * 64 + c8,         \
               Vs + (bi) * 4096 + ch0 * 512);                                  \
    async_ld16(vbase + (size_t)(ch0 * 8 + 8 + r8) * 1024 + (kt) * 64 + c8,     \
               Vs + (bi) * 4096 + ch0 * 512 + 512);                            \
  } while (0)

  const int qrow_l = wave * 32 + q31;  // this lane's query row in tile
  // Q B-frags straight from global: frag ks = q-row k-slice [ks*16+h*8, +8)
  bf16x8 qf[4];
#pragma unroll
  for (int ks = 0; ks < 4; ks++)
    qf[ks] = *(const bf16x8*)(qbase + (size_t)qrow_l * 64 + ks * 16 + h * 8);
  STAGEKV(0, 0);
  asm volatile("s_waitcnt vmcnt(0)" ::: "memory");
  __builtin_amdgcn_sched_barrier(0);
  __builtin_amdgcn_s_barrier();
  __builtin_amdgcn_sched_barrier(0);

  float lsum = 0.f;
  f32x16 oacc[2] = {};
  for (int kt = 0; kt < 16; kt++) {
    const int cbuf = kt & 1;
    if (kt + 1 < 16) STAGEKV(kt + 1, cbuf ^ 1);
    const unsigned short* Kb = Ks + cbuf * 4096;
    const unsigned short* Vb = Vs + cbuf * 4096;
    // S^T = K.Q^T : 2 key tiles x 4 ksteps
    f32x16 st[2] = {{}, {}};
#pragma unroll
    for (int T = 0; T < 2; T++) {
      const int krow = 32 * T + q31;
      const int ksw = krow & 7;
#pragma unroll
      for (int ks = 0; ks < 4; ks++) {
        const bf16x8 kf = *(const bf16x8*)(Kb + krow * 64 + (((2 * ks + h) ^ ksw)) * 8);
        st[T] = __builtin_amdgcn_mfma_f32_32x32x16_bf16(kf, qf[ks], st[T], 0, 0, 0);
      }
    }
    // p = exp2(s) (q pre-scaled by log2e/8); pack bf16 pairs per group
    u32 pk[2][4][2];
#pragma unroll
    for (int T = 0; T < 2; T++)
#pragma unroll
      for (int g = 0; g < 4; g++)
#pragma unroll
        for (int e = 0; e < 2; e++) {
          const float plo = exp2fast(st[T][4 * g + 2 * e]);
          const float phi = exp2fast(st[T][4 * g + 2 * e + 1]);
          lsum += plo + phi;
          pk[T][g][e] = (u32)f2b(plo) | ((u32)f2b(phi) << 16);
        }
    // half-wave exchange of the cross quads
    u32 rcv[2][4];
#pragma unroll
    for (int T = 0; T < 2; T++) {
      const u32 p0 = h ? pk[T][0][0] : pk[T][1][0];
      const u32 p1 = h ? pk[T][0][1] : pk[T][1][1];
      const u32 p2 = h ? pk[T][2][0] : pk[T][3][0];
      const u32 p3 = h ? pk[T][2][1] : pk[T][3][1];
      rcv[T][0] = (u32)__shfl_xor((int)p0, 32, 64);
      rcv[T][1] = (u32)__shfl_xor((int)p1, 32, 64);
      rcv[T][2] = (u32)__shfl_xor((int)p2, 32, 64);
      rcv[T][3] = (u32)__shfl_xor((int)p3, 32, 64);
    }
    // O += P.V
#pragma unroll
    for (int tt = 0; tt < 4; tt++) {
      const int T = tt >> 1, uu = tt & 1;
      union { u32 u[4]; bf16x8 v; } af;
      if (h == 0) {
        af.u[0] = pk[T][2 * uu][0];
        af.u[1] = pk[T][2 * uu][1];
        af.u[2] = rcv[T][2 * uu];
        af.u[3] = rcv[T][2 * uu + 1];
      } else {
        af.u[0] = rcv[T][2 * uu];
        af.u[1] = rcv[T][2 * uu + 1];
        af.u[2] = pk[T][2 * uu + 1][0];
        af.u[3] = pk[T][2 * uu + 1][1];
      }
#pragma unroll
      for (int ot = 0; ot < 2; ot++) {
        const int vrow = 32 * ot + q31;
        const int vsw = vrow & 7;
        const bf16x8 bv = *(const bf16x8*)(Vb + vrow * 64 + (((2 * tt + h) ^ vsw)) * 8);
        oacc[ot] = __builtin_amdgcn_mfma_f32_32x32x16_bf16(af.v, bv, oacc[ot], 0, 0, 0);
      }
    }
    if (kt + 1 < 16) {
      __builtin_amdgcn_sched_barrier(0);
      asm volatile("s_waitcnt vmcnt(0)" ::: "memory");  // kt+1 resident
      __builtin_amdgcn_sched_barrier(0);
      __builtin_amdgcn_s_barrier();  // all waves done reading buf[cbuf]
      __builtin_amdgcn_sched_barrier(0);
    }
  }
#undef STAGEKV
  // epilogue: full row-sum, normalize, store
  lsum += __shfl_xor(lsum, 32, 64);
  if (h == 0) wl[wave * 32 + q31] = lsum;
  const int qglob = seg * 1024 + qt * 128 + wave * 32;
#pragma unroll
  for (int g = 0; g < 4; g++) {
    const float4 lv = *(const float4*)&wl[wave * 32 + 8 * g + 4 * h];
#pragma unroll
    for (int m = 0; m < 4; m++) {
      const int r16 = 4 * g + m;
      const int qrow = qglob + m + 8 * g + 4 * h;
      const float invl = rcpfast((&lv.x)[m]);
#pragma unroll
      for (int ot = 0; ot < 2; ot++)
        out[(size_t)qrow * 1024 + head * 64 + 32 * ot + q31] = f2b(oacc[ot][r16] * invl);
    }
  }
}

// ---------------------------------------------------------------------------
extern "C" void kernel_launch(void* const* d_in, const int* in_sizes, int n_in,
                              void* d_out, int out_size, void* d_ws, size_t ws_size,
                              hipStream_t stream) {
  (void)in_sizes; (void)n_in; (void)out_size; (void)ws_size;
  const float* x    = (const float*)d_in[0];
  const float* wqkv = (const float*)d_in[1];
  const float* wo   = (const float*)d_in[2];
  const float* ln0g = (const float*)d_in[3];
  const float* ln0b = (const float*)d_in[4];
  const float* ln1g = (const float*)d_in[5];
  const float* ln1b = (const float*)d_in[6];
  const float* fc0w = (const float*)d_in[7];
  const float* fc0b = (const float*)d_in[8];
  const float* fc1w = (const float*)d_in[9];
  const float* fc1b = (const float*)d_in[10];
  const float* rc   = (const float*)d_in[11];
  const float* rsn  = (const float*)d_in[12];
  float* out = (float*)d_out;
  char* w = (char*)d_ws;
  const size_t MB = 1u << 20;
  unsigned short* hb    = (unsigned short*)(w + 0);
  unsigned short* bqkv  = (unsigned short*)(w + 16 * MB);
  unsigned short* bwo   = (unsigned short*)(w + 22 * MB);
  unsigned short* bfc0  = (unsigned short*)(w + 24 * MB);
  unsigned short* bfc1  = (unsigned short*)(w + 32 * MB);
  unsigned short* qhb   = (unsigned short*)(w + 40 * MB);
  unsigned short* khb   = (unsigned short*)(w + 56 * MB);
  unsigned short* vtb   = (unsigned short*)(w + 72 * MB);
  unsigned short* attnb = (unsigned short*)(w + 88 * MB);
  unsigned short* qkvb  = (unsigned short*)(w + 104 * MB);
  unsigned short* midb  = (unsigned short*)(w + 104 * MB);  // alias, qkvb dead

  // 1: weight casts + LN0 (one dispatch)
  castln_kernel<<<20480, 256, 0, stream>>>(wqkv, wo, fc0w, fc1w, bqkv,
                                           x, ln0g, ln0b, hb);
  // 2: QKV = hb @ wqkv^T   (p8, 256x256, 384 blk = 1.5/CU)
  gemm_p8<4, 12, 256><<<384, 512, 0, stream>>>(hb, bqkv, 8192, 3072, 1024,
                                               nullptr, qkvb, nullptr, nullptr);
  // 3: RoPE + V-transpose (one dispatch)
  ropevt_kernel<<<6144, 256, 0, stream>>>(qkvb, rc, rsn, qhb, khb, vtb);
  // 4: attention (K/V double-buffered)
  attn_kernel<<<1024, 256, 0, stream>>>(qhb, khb, vtb, attnb);
  // 5: WO: out = attn @ wo^T + x   (p8, 128x256, 256 blk = 1.0/CU)
  gemm_p8<1, 4, 128><<<256, 512, 0, stream>>>(attnb, bwo, 8192, 1024, 1024,
                                              out, nullptr, x, nullptr);
  // 6: LN1
  ln_kernel<<<8192, 256, 0, stream>>>(out, ln1g, ln1b, hb);
  // 7: FC0 (+bias, GELU) -> midb   (bt8, 256x256, 512 blk = 2.0/CU)
  gemm_bt8<2, 16, 256><<<512, 512, 0, stream>>>(hb, bfc0, 8192, 4096, 1024,
                                                nullptr, midb, nullptr, fc0b);
  // 8: FC1: out = mid @ fc1^T + bias + out   (p8, 128x256, 256 blk, K=4096)
  gemm_p8<3, 4, 128><<<256, 512, 0, stream>>>(midb, bfc1, 8192, 1024, 4096,
                                              out, nullptr, out, fc1b);
}